// Round 7
// baseline (4445.976 us; speedup 1.0000x reference)
//
#include <hip/hip_runtime.h>
#include <cstdint>

// GptOssExpertsLinear: E=16, H=D=2880, T=2048.
// out[t,h] = sum_e rw[t,e] * ( act(x@Wg[e]+bg, x@Wu[e]+bu) @ Wd[e] + bd )
// R7: B streams straight from global (L2) into MFMA B-fragments (no B LDS).
// A stays global_load_lds double-buffered (XOR-swizzled source). LDS=32KB,
// launch_bounds(256,3) targets 12 waves/CU. Weights pre-transposed to bf16
// [n][k] by tcvt (gate/up paired at 48-col blocks). Down: per-expert fp32
// partials + reduce.

#define ALPHA 1.702f
#define LIMIT 7.0f

static constexpr int E = 16;
static constexpr int H = 2880;
static constexpr int D = 2880;
static constexpr int T = 2048;
static constexpr int NKT = H / 64;   // 45 K-steps

typedef float        f32x4  __attribute__((ext_vector_type(4)));
typedef short        bf16x8 __attribute__((ext_vector_type(8)));

#define MFMA_BF16(a,b,c) __builtin_amdgcn_mfma_f32_16x16x32_bf16((a),(b),(c),0,0,0)
#define SBAR()        __builtin_amdgcn_s_barrier()
#define SCHED_FENCE() __builtin_amdgcn_sched_barrier(0)

__device__ __forceinline__ unsigned short f2bf(float f){
  unsigned u = __builtin_bit_cast(unsigned, f);
  u += 0x7fffu + ((u >> 16) & 1u);
  return (unsigned short)(u >> 16);
}
__device__ __forceinline__ unsigned pack2(float a, float b){
  return (unsigned)f2bf(a) | ((unsigned)f2bf(b) << 16);
}

__device__ __forceinline__ void gload_lds16(const void* g, void* l){
  __builtin_amdgcn_global_load_lds((const __attribute__((address_space(1))) unsigned*)g,
                                   (__attribute__((address_space(3))) unsigned*)l,
                                   16, 0, 0);
}

// x fp32 -> bf16, 8 elems/thread
__global__ void cvt_kernel(const float* __restrict__ in, unsigned short* __restrict__ ob, int n8){
  int i = blockIdx.x * 256 + threadIdx.x;
  if (i < n8){
    float4 a = ((const float4*)in)[2*i];
    float4 b = ((const float4*)in)[2*i+1];
    uint4 o;
    o.x = pack2(a.x, a.y); o.y = pack2(a.z, a.w);
    o.z = pack2(b.x, b.y); o.w = pack2(b.z, b.w);
    ((uint4*)ob)[i] = o;
  }
}

// W[2880][2880] fp32 -> bf16 transpose with row remap.
// mode 0: dst row = (c/48)*96 + c%48       (gate half, 48-col pairing)
// mode 1: dst row = (c/48)*96 + c%48 + 48  (up half)
// mode 2: dst row = c                      (plain transpose, down weights)
__global__ __launch_bounds__(256) void tcvt_kernel(
    const float* __restrict__ src, unsigned short* __restrict__ dst,
    int mode, size_t dstExpStride)
{
  __shared__ unsigned short tl[64*72];
  const int t = threadIdx.x;
  const float* s = src + (size_t)blockIdx.z * H * D;
  unsigned short* o = dst + (size_t)blockIdx.z * dstExpStride;
  const int r0 = blockIdx.x * 64, c0 = blockIdx.y * 64;

  int rr = t >> 2;
  #pragma unroll
  for (int p = 0; p < 4; ++p){
    int cc = ((t & 3) + p*4) * 4;
    float4 v = *(const float4*)(s + (size_t)(r0 + rr)*D + c0 + cc);
    tl[(cc+0)*72 + rr] = f2bf(v.x);
    tl[(cc+1)*72 + rr] = f2bf(v.y);
    tl[(cc+2)*72 + rr] = f2bf(v.z);
    tl[(cc+3)*72 + rr] = f2bf(v.w);
  }
  __syncthreads();
  #pragma unroll
  for (int p = 0; p < 2; ++p){
    int task = p*256 + t;
    int cl = task >> 3, ch = task & 7;
    int c = c0 + cl;
    int rowp = (mode < 2) ? ((c/48)*96 + (c%48) + mode*48) : c;
    bf16x8 v = *(const bf16x8*)&tl[cl*72 + ch*8];
    *(bf16x8*)(o + (size_t)rowp*H + r0 + ch*8) = v;
  }
}

// sum the 16 per-expert partials -> out
__global__ void reduce_kernel(const float* __restrict__ p, float* __restrict__ out, int n4){
  int i = blockIdx.x * 256 + threadIdx.x;
  if (i < n4){
    f32x4 a = ((const f32x4*)p)[i];
    #pragma unroll
    for (int g = 1; g < E; ++g)
      a += ((const f32x4*)(p + (size_t)g * T * H))[i];
    ((f32x4*)out)[i] = a;
  }
}

// ---------------- gate+up fused GEMM + activation ----------------
// grid (16, 30, ec); 4 waves (2M x 2N); wave tile 64 x 96' (48 gate + 48 up).
// A: LDS dbuf via DMA. B: direct global->reg fragments (L2-resident panels).
__global__ __launch_bounds__(256, 3) void gateup_kernel(
    const unsigned short* __restrict__ xb,    // [T][H] bf16
    const unsigned short* __restrict__ wGU,   // [ec][5760'][H] paired bf16
    const float* __restrict__ bg,
    const float* __restrict__ bu,
    unsigned short* __restrict__ inter,       // [ec][T][D] bf16
    int e0)
{
  __shared__ short As[2][128*64];   // 32KB total

  const int t = threadIdx.x, lane = t & 63, wv = t >> 6;
  const int wm = wv >> 1, wn = wv & 1;

  int nbx = gridDim.x, nby = gridDim.y;
  int lin = blockIdx.x + nbx*(blockIdx.y + nby*blockIdx.z);
  int per = (nbx*nby*gridDim.z) >> 3;
  int id2 = (lin & 7)*per + (lin >> 3);
  int bx = id2 % nbx; int rem = id2 / nbx;
  int by = rem % nby; int ez = rem / nby;

  const int trow0 = bx * 128;
  const int e = e0 + ez;
  const unsigned short* wg = wGU + (size_t)ez * 2 * D * H;
  // per-lane B fragment base: row = nbase + (lane&15), k-chunk = lane>>4
  const int nbase = by * 192 + wn * 96;
  const unsigned short* bp = wg + (size_t)(nbase + (lane & 15)) * H + ((lane >> 4) * 8);

  f32x4 acc[4][6];
  #pragma unroll
  for (int i = 0; i < 4; ++i)
    #pragma unroll
    for (int j = 0; j < 6; ++j) acc[i][j] = (f32x4){0.f,0.f,0.f,0.f};

  auto stageA = [&](int kt, int buf){
    #pragma unroll
    for (int i = 0; i < 4; ++i){
      int task = i*256 + t, row = task >> 3, ch = task & 7, sch = ch ^ (row & 7);
      gload_lds16(xb + (size_t)(trow0 + row)*H + kt*64 + sch*8, &As[buf][task*8]);
    }
  };

  stageA(0, 0);   // 4 vmem in flight

  for (int kt = 0; kt < NKT; ++kt){
    int cur = kt & 1, nxt = cur ^ 1;
    int ktn = (kt+1 < NKT) ? kt+1 : kt;
    stageA(ktn, nxt);                              // 4 more (8 outstanding)
    asm volatile("s_waitcnt vmcnt(4)" ::: "memory");  // A(kt) landed (B all retired)
    SCHED_FENCE(); SBAR(); SCHED_FENCE();
    #pragma unroll
    for (int kk = 0; kk < 2; ++kk){
      // B fragments direct from global (L2)
      bf16x8 fb[6];
      #pragma unroll
      for (int ni = 0; ni < 6; ++ni)
        fb[ni] = *(const bf16x8*)(bp + (size_t)ni*16*H + kt*64 + kk*32);
      bf16x8 af[4];
      #pragma unroll
      for (int mi = 0; mi < 4; ++mi){
        int row = wm*64 + mi*16 + (lane & 15);
        int pc  = (kk*4 + (lane>>4)) ^ (row & 7);
        af[mi] = *(const bf16x8*)&As[cur][row*64 + pc*8];
      }
      #pragma unroll
      for (int ni = 0; ni < 6; ++ni)
        #pragma unroll
        for (int mi = 0; mi < 4; ++mi)
          acc[mi][ni] = MFMA_BF16(af[mi], fb[ni], acc[mi][ni]);
    }
    SBAR();
  }
  asm volatile("s_waitcnt vmcnt(0)" ::: "memory");

  // epilogue: ni g (gate) pairs with ni g+3 (up), same d
  const float* bgp = bg + (size_t)e * D;
  const float* bup = bu + (size_t)e * D;
  unsigned short* ip = inter + (size_t)ez * T * D;
  #pragma unroll
  for (int g = 0; g < 3; ++g){
    int d = by*96 + wn*48 + g*16 + (lane & 15);
    float bgv = bgp[d], buv = bup[d];
    #pragma unroll
    for (int mi = 0; mi < 4; ++mi){
      #pragma unroll
      for (int r = 0; r < 4; ++r){
        int trw = trow0 + wm*64 + mi*16 + (lane >> 4)*4 + r;
        float gv = acc[mi][g][r] + bgv;
        float uv = acc[mi][g+3][r] + buv;
        gv = fminf(gv, LIMIT);
        uv = fminf(fmaxf(uv, -LIMIT), LIMIT);
        float glu = gv / (1.f + __expf(-ALPHA * gv));
        ip[(size_t)trw * D + d] = f2bf((uv + 1.f) * glu);
      }
    }
  }
}

// ---------------- down GEMM -> per-expert weighted partial ----------------
// grid (16, 15, ec); 4 waves (2M x 2N); wave tile 64 x 96; B direct from L2.
__global__ __launch_bounds__(256, 3) void down_kernel(
    const unsigned short* __restrict__ inter, // [ec][T][D] bf16
    const unsigned short* __restrict__ wdT,   // [ec][H][D] bf16 (n-major)
    const float* __restrict__ bd,
    const float* __restrict__ rw,             // [T][E]
    float* __restrict__ pout,                 // [E][T][H] fp32 partials
    int e0)
{
  __shared__ short As[2][128*64];   // 32KB

  const int t = threadIdx.x, lane = t & 63, wv = t >> 6;
  const int wm = wv >> 1, wn = wv & 1;

  int nbx = gridDim.x, nby = gridDim.y;
  int lin = blockIdx.x + nbx*(blockIdx.y + nby*blockIdx.z);
  int per = (nbx*nby*gridDim.z) >> 3;
  int id2 = (lin & 7)*per + (lin >> 3);
  int bx = id2 % nbx; int rem = id2 / nbx;
  int by = rem % nby; int ez = rem / nby;

  const int trow0 = bx * 128;
  const int e = e0 + ez;
  const unsigned short* ap = inter + (size_t)ez * T * D;
  const unsigned short* wd = wdT + (size_t)ez * H * D;
  const int nbase = by * 192 + wn * 96;
  const unsigned short* bp = wd + (size_t)(nbase + (lane & 15)) * D + ((lane >> 4) * 8);

  f32x4 acc[4][6];
  #pragma unroll
  for (int i = 0; i < 4; ++i)
    #pragma unroll
    for (int j = 0; j < 6; ++j) acc[i][j] = (f32x4){0.f,0.f,0.f,0.f};

  auto stageA = [&](int kt, int buf){
    #pragma unroll
    for (int i = 0; i < 4; ++i){
      int task = i*256 + t, row = task >> 3, ch = task & 7, sch = ch ^ (row & 7);
      gload_lds16(ap + (size_t)(trow0 + row)*D + kt*64 + sch*8, &As[buf][task*8]);
    }
  };

  stageA(0, 0);

  for (int kt = 0; kt < NKT; ++kt){
    int cur = kt & 1, nxt = cur ^ 1;
    int ktn = (kt+1 < NKT) ? kt+1 : kt;
    stageA(ktn, nxt);
    asm volatile("s_waitcnt vmcnt(4)" ::: "memory");
    SCHED_FENCE(); SBAR(); SCHED_FENCE();
    #pragma unroll
    for (int kk = 0; kk < 2; ++kk){
      bf16x8 fb[6];
      #pragma unroll
      for (int ni = 0; ni < 6; ++ni)
        fb[ni] = *(const bf16x8*)(bp + (size_t)ni*16*D + kt*64 + kk*32);
      bf16x8 af[4];
      #pragma unroll
      for (int mi = 0; mi < 4; ++mi){
        int row = wm*64 + mi*16 + (lane & 15);
        int pc  = (kk*4 + (lane>>4)) ^ (row & 7);
        af[mi] = *(const bf16x8*)&As[cur][row*64 + pc*8];
      }
      #pragma unroll
      for (int ni = 0; ni < 6; ++ni)
        #pragma unroll
        for (int mi = 0; mi < 4; ++mi)
          acc[mi][ni] = MFMA_BF16(af[mi], fb[ni], acc[mi][ni]);
    }
    SBAR();
  }
  asm volatile("s_waitcnt vmcnt(0)" ::: "memory");

  // epilogue: pout[e] = rw[t,e] * (acc + bd)
  const float* bdp = bd + (size_t)e * H;
  float* pp = pout + (size_t)e * T * H;
  #pragma unroll
  for (int ni = 0; ni < 6; ++ni){
    int h = nbase + ni*16 + (lane & 15);
    float bdv = bdp[h];
    #pragma unroll
    for (int mi = 0; mi < 4; ++mi){
      #pragma unroll
      for (int r = 0; r < 4; ++r){
        int trw = trow0 + wm*64 + mi*16 + (lane >> 4)*4 + r;
        float rv = rw[trw*E + e];
        pp[(size_t)trw * H + h] = rv * (acc[mi][ni][r] + bdv);
      }
    }
  }
}

extern "C" void kernel_launch(void* const* d_in, const int* in_sizes, int n_in,
                              void* d_out, int out_size, void* d_ws, size_t ws_size,
                              hipStream_t stream) {
  const float* hs  = (const float*)d_in[0];
  const float* rwt = (const float*)d_in[1];
  const float* Wg  = (const float*)d_in[2];
  const float* bg  = (const float*)d_in[3];
  const float* Wu  = (const float*)d_in[4];
  const float* bu  = (const float*)d_in[5];
  const float* Wd  = (const float*)d_in[6];
  const float* bd  = (const float*)d_in[7];
  float* out = (float*)d_out;

  const size_t xbytes = (size_t)T * H * 2;          // 11.8 MB
  const size_t poutB  = (size_t)E * T * H * 4;      // 377 MB
  const size_t interB = (size_t)T * D * 2;          // 11.8 MB / expert
  const size_t guB    = (size_t)2 * D * H * 2;      // 33.2 MB / expert (paired)
  const size_t perE   = interB + guB;               // ~45 MB / expert

  long long avail = (long long)ws_size - (long long)(xbytes + poutB);
  int EC = (int)(avail / (long long)perE);
  if (EC < 1) EC = 1;
  if (EC > E) EC = E;

  unsigned short* xb    = (unsigned short*)d_ws;
  float*          pout  = (float*)((char*)d_ws + xbytes);
  unsigned short* inter = (unsigned short*)((char*)d_ws + xbytes + poutB);
  unsigned short* wGU   = (unsigned short*)((char*)d_ws + xbytes + poutB + (size_t)EC*interB);
  // wdT aliases wGU (stream-serialized: gateup consumes wGU before down tcvt)

  cvt_kernel<<<(T*H/8 + 255)/256, 256, 0, stream>>>(hs, xb, T*H/8);

  for (int e0 = 0; e0 < E; e0 += EC){
    int ec = (E - e0 < EC) ? (E - e0) : EC;
    tcvt_kernel<<<dim3(45,45,ec), 256, 0, stream>>>(Wg + (size_t)e0*H*D, wGU, 0, (size_t)2*D*H);
    tcvt_kernel<<<dim3(45,45,ec), 256, 0, stream>>>(Wu + (size_t)e0*H*D, wGU, 1, (size_t)2*D*H);
    gateup_kernel<<<dim3(16, 30, ec), 256, 0, stream>>>(xb, wGU, bg, bu, inter, e0);
    tcvt_kernel<<<dim3(45,45,ec), 256, 0, stream>>>(Wd + (size_t)e0*D*H, wGU, 2, (size_t)D*H);
    down_kernel<<<dim3(16, 15, ec), 256, 0, stream>>>(inter, wGU, bd, rwt, pout, e0);
  }
  reduce_kernel<<<(T*H/4 + 255)/256, 256, 0, stream>>>(pout, out, T*H/4);
}

// Round 8
// 3537.028 us; speedup vs baseline: 1.2570x; 1.2570x over previous
//
#include <hip/hip_runtime.h>
#include <cstdint>

// GptOssExpertsLinear: E=16, H=D=2880, T=2048.
// out[t,h] = sum_e rw[t,e] * ( act(x@Wg[e]+bg, x@Wu[e]+bu) @ Wd[e] + bd )
// R8: R5 geometry (proven 930 TF, 80KB LDS, 2 blocks/CU) with 4-phase
// K-step schedule: per phase {stage-issue slice; ds_read slice; lgkmcnt(0);
// setprio(1); 12 MFMA; setprio(0); barrier}, counted vmcnt(3) once per
// K-step (never 0 in-loop). T3+T4+T5 applied to the m97-class loop.

#define ALPHA 1.702f
#define LIMIT 7.0f

static constexpr int E = 16;
static constexpr int H = 2880;
static constexpr int D = 2880;
static constexpr int T = 2048;
static constexpr int NKT = H / 64;   // 45 K-steps
static constexpr int NG  = 4;        // down expert groups (partial buffers)

typedef float        f32x4  __attribute__((ext_vector_type(4)));
typedef short        bf16x8 __attribute__((ext_vector_type(8)));

#define MFMA_BF16(a,b,c) __builtin_amdgcn_mfma_f32_16x16x32_bf16((a),(b),(c),0,0,0)
#define SBAR()        __builtin_amdgcn_s_barrier()
#define SCHED_FENCE() __builtin_amdgcn_sched_barrier(0)
#define PRIO1()       __builtin_amdgcn_s_setprio(1)
#define PRIO0()       __builtin_amdgcn_s_setprio(0)
#define LGK0()        asm volatile("s_waitcnt lgkmcnt(0)" ::: "memory")

__device__ __forceinline__ unsigned short f2bf(float f){
  unsigned u = __builtin_bit_cast(unsigned, f);
  u += 0x7fffu + ((u >> 16) & 1u);
  return (unsigned short)(u >> 16);
}
__device__ __forceinline__ unsigned pack2(float a, float b){
  return (unsigned)f2bf(a) | ((unsigned)f2bf(b) << 16);
}

__device__ __forceinline__ void gload_lds16(const void* g, void* l){
  __builtin_amdgcn_global_load_lds((const __attribute__((address_space(1))) unsigned*)g,
                                   (__attribute__((address_space(3))) unsigned*)l,
                                   16, 0, 0);
}

// x fp32 -> bf16, 8 elems/thread
__global__ void cvt_kernel(const float* __restrict__ in, unsigned short* __restrict__ ob, int n8){
  int i = blockIdx.x * 256 + threadIdx.x;
  if (i < n8){
    float4 a = ((const float4*)in)[2*i];
    float4 b = ((const float4*)in)[2*i+1];
    uint4 o;
    o.x = pack2(a.x, a.y); o.y = pack2(a.z, a.w);
    o.z = pack2(b.x, b.y); o.w = pack2(b.z, b.w);
    ((uint4*)ob)[i] = o;
  }
}

// W[2880][2880] fp32 -> W^T[2880][2880] bf16, 64x64 tiles via LDS.
__global__ __launch_bounds__(256) void tcvt_kernel(
    const float* __restrict__ src, unsigned short* __restrict__ dst)
{
  __shared__ unsigned short tl[64*72];
  const int t = threadIdx.x;
  const size_t mo = (size_t)blockIdx.z * H * D;
  const int r0 = blockIdx.x * 64, c0 = blockIdx.y * 64;
  const float* s = src + mo;
  unsigned short* o = dst + mo;

  int rr = t >> 2;
  #pragma unroll
  for (int p = 0; p < 4; ++p){
    int cc = ((t & 3) + p*4) * 4;
    float4 v = *(const float4*)(s + (size_t)(r0 + rr)*D + c0 + cc);
    tl[(cc+0)*72 + rr] = f2bf(v.x);
    tl[(cc+1)*72 + rr] = f2bf(v.y);
    tl[(cc+2)*72 + rr] = f2bf(v.z);
    tl[(cc+3)*72 + rr] = f2bf(v.w);
  }
  __syncthreads();
  #pragma unroll
  for (int p = 0; p < 2; ++p){
    int task = p*256 + t;
    int cl = task >> 3, ch = task & 7;
    bf16x8 v = *(const bf16x8*)&tl[cl*72 + ch*8];
    *(bf16x8*)(o + (size_t)(c0 + cl)*H + r0 + ch*8) = v;
  }
}

// sum the NG down partials -> out
__global__ void reduce_kernel(const float* __restrict__ p, float* __restrict__ out, int n4){
  int i = blockIdx.x * 256 + threadIdx.x;
  if (i < n4){
    f32x4 a = ((const f32x4*)p)[i];
    #pragma unroll
    for (int g = 1; g < NG; ++g)
      a += ((const f32x4*)(p + (size_t)g * T * H))[i];
    ((f32x4*)out)[i] = a;
  }
}

// ---------------- gate+up fused GEMM + activation ----------------
// grid (16, 30, ec); 256 thr = 4 waves (2m x 2n); wave tile 64x48 (x2 mats).
__global__ __launch_bounds__(256, 2) void gateup_kernel(
    const unsigned short* __restrict__ xb,    // [T][H] bf16
    const unsigned short* __restrict__ wgT,   // [ec][D][H] bf16 (n-major)
    const float* __restrict__ bg,
    const unsigned short* __restrict__ wuT,   // [ec][D][H] bf16
    const float* __restrict__ bu,
    unsigned short* __restrict__ inter,       // [ec][T][D] bf16
    int e0)
{
  __shared__ short As[2][128*64];   // 32KB
  __shared__ short Bg[2][96*64];    // 24KB
  __shared__ short Bu[2][96*64];    // 24KB => 80KB, 2 blocks/CU

  const int t = threadIdx.x, lane = t & 63, wv = t >> 6;
  const int wm = wv >> 1, wn = wv & 1;

  int nbx = gridDim.x, nby = gridDim.y;
  int lin = blockIdx.x + nbx*(blockIdx.y + nby*blockIdx.z);
  int per = (nbx*nby*gridDim.z) >> 3;
  int id2 = (lin & 7)*per + (lin >> 3);
  int bx = id2 % nbx; int rem = id2 / nbx;
  int by = rem % nby; int ez = rem / nby;

  const int trow0 = bx * 128, ncol0 = by * 96;
  const int e = e0 + ez;
  const unsigned short* wg = wgT + (size_t)ez * D * H;
  const unsigned short* wu = wuT + (size_t)ez * D * H;

  f32x4 accg[4][3], accu[4][3];
  #pragma unroll
  for (int i = 0; i < 4; ++i)
    #pragma unroll
    for (int j = 0; j < 3; ++j){
      accg[i][j] = (f32x4){0.f,0.f,0.f,0.f};
      accu[i][j] = (f32x4){0.f,0.f,0.f,0.f};
    }

  // stage slices: A chunk i in 0..3 ; B pair j in 0..2 (g and/or u)
  auto sA = [&](int kt, int buf, int i){
    int task = i*256 + t, row = task >> 3, ch = task & 7, sch = ch ^ (row & 7);
    gload_lds16(xb + (size_t)(trow0 + row)*H + kt*64 + sch*8, &As[buf][task*8]);
  };
  auto sBg = [&](int kt, int buf, int j){
    int task = j*256 + t, row = task >> 3, ch = task & 7, sch = ch ^ (row & 7);
    gload_lds16(wg + (size_t)(ncol0 + row)*H + kt*64 + sch*8, &Bg[buf][task*8]);
  };
  auto sBu = [&](int kt, int buf, int j){
    int task = j*256 + t, row = task >> 3, ch = task & 7, sch = ch ^ (row & 7);
    gload_lds16(wu + (size_t)(ncol0 + row)*H + kt*64 + sch*8, &Bu[buf][task*8]);
  };

  auto readAf = [&](bf16x8* af, int cur, int kk){
    #pragma unroll
    for (int mi = 0; mi < 4; ++mi){
      int row = wm*64 + mi*16 + (lane & 15);
      int pc  = (kk*4 + (lane>>4)) ^ (row & 7);
      af[mi] = *(const bf16x8*)&As[cur][row*64 + pc*8];
    }
  };
  auto readF = [&](bf16x8* fr, const short* B, int kk){
    #pragma unroll
    for (int ni = 0; ni < 3; ++ni){
      int row = (wn*3 + ni)*16 + (lane & 15);
      int pc  = (kk*4 + (lane>>4)) ^ (row & 7);
      fr[ni] = *(const bf16x8*)&B[row*64 + pc*8];
    }
  };

  // full stage of K-step 0
  #pragma unroll
  for (int i = 0; i < 4; ++i) sA(0, 0, i);
  #pragma unroll
  for (int j = 0; j < 3; ++j){ sBg(0, 0, j); sBu(0, 0, j); }   // 10 in flight

  for (int kt = 0; kt < NKT; ++kt){
    int cur = kt & 1, nxt = cur ^ 1;
    int ktn = (kt+1 < NKT) ? kt+1 : kt;
    bf16x8 af[4], fr[3];
    // ---- P0: A0-2 issue; wait stage(kt); af0 x fg0
    sA(ktn, nxt, 0); sA(ktn, nxt, 1); sA(ktn, nxt, 2);
    asm volatile("s_waitcnt vmcnt(3)" ::: "memory");
    SCHED_FENCE(); SBAR(); SCHED_FENCE();
    readAf(af, cur, 0); readF(fr, Bg[cur], 0);
    LGK0(); SCHED_FENCE();
    PRIO1();
    #pragma unroll
    for (int ni = 0; ni < 3; ++ni)
      #pragma unroll
      for (int mi = 0; mi < 4; ++mi)
        accg[mi][ni] = MFMA_BF16(af[mi], fr[ni], accg[mi][ni]);
    PRIO0(); SBAR();
    // ---- P1: A3,Bg0,Bu0 issue; af0 x fu0
    sA(ktn, nxt, 3); sBg(ktn, nxt, 0); sBu(ktn, nxt, 0);
    readF(fr, Bu[cur], 0);
    LGK0(); SCHED_FENCE();
    PRIO1();
    #pragma unroll
    for (int ni = 0; ni < 3; ++ni)
      #pragma unroll
      for (int mi = 0; mi < 4; ++mi)
        accu[mi][ni] = MFMA_BF16(af[mi], fr[ni], accu[mi][ni]);
    PRIO0(); SBAR();
    // ---- P2: Bg1,Bu1,Bg2 issue; af1 x fg1
    sBg(ktn, nxt, 1); sBu(ktn, nxt, 1); sBg(ktn, nxt, 2);
    readAf(af, cur, 1); readF(fr, Bg[cur], 1);
    LGK0(); SCHED_FENCE();
    PRIO1();
    #pragma unroll
    for (int ni = 0; ni < 3; ++ni)
      #pragma unroll
      for (int mi = 0; mi < 4; ++mi)
        accg[mi][ni] = MFMA_BF16(af[mi], fr[ni], accg[mi][ni]);
    PRIO0(); SBAR();
    // ---- P3: Bu2 issue; af1 x fu1
    sBu(ktn, nxt, 2);
    readF(fr, Bu[cur], 1);
    LGK0(); SCHED_FENCE();
    PRIO1();
    #pragma unroll
    for (int ni = 0; ni < 3; ++ni)
      #pragma unroll
      for (int mi = 0; mi < 4; ++mi)
        accu[mi][ni] = MFMA_BF16(af[mi], fr[ni], accu[mi][ni]);
    PRIO0(); SBAR();
  }
  asm volatile("s_waitcnt vmcnt(0)" ::: "memory");

  // epilogue: bias + clamp + glu -> inter bf16
  const float* bgp = bg + (size_t)e * D;
  const float* bup = bu + (size_t)e * D;
  unsigned short* ip = inter + (size_t)ez * T * D;
  #pragma unroll
  for (int ni = 0; ni < 3; ++ni){
    int d = ncol0 + wn*48 + ni*16 + (lane & 15);
    float bgv = bgp[d], buv = bup[d];
    #pragma unroll
    for (int mi = 0; mi < 4; ++mi){
      #pragma unroll
      for (int r = 0; r < 4; ++r){
        int trw = trow0 + wm*64 + mi*16 + (lane >> 4)*4 + r;
        float g = accg[mi][ni][r] + bgv;
        float u = accu[mi][ni][r] + buv;
        g = fminf(g, LIMIT);
        u = fminf(fmaxf(u, -LIMIT), LIMIT);
        float glu = g / (1.f + __expf(-ALPHA * g));
        ip[(size_t)trw * D + d] = f2bf((u + 1.f) * glu);
      }
    }
  }
}

// ---------------- down GEMM + routing-weighted accumulate ----------------
// grid (16, 15, NG); tile 128x192; wave tile 64x96. Group g handles experts
// e0+g, e0+g+4, ... accumulating rw-weighted results into pout[g] (fp32).
__global__ __launch_bounds__(256, 2) void down_kernel(
    const unsigned short* __restrict__ inter, // [ec][T][D] bf16
    const unsigned short* __restrict__ wdT,   // [ec][H][D] bf16 (n-major)
    const float* __restrict__ bd,
    const float* __restrict__ rw,             // [T][E]
    float* __restrict__ pout,                 // [NG][T][H] fp32 partials
    int e0, int ec)
{
  __shared__ short As[2][128*64];   // 32KB
  __shared__ short Bs[2][192*64];   // 48KB => 80KB, 2 blocks/CU

  const int t = threadIdx.x, lane = t & 63, wv = t >> 6;
  const int wm = wv >> 1, wn = wv & 1;

  int nbx = gridDim.x, nby = gridDim.y;
  int lin = blockIdx.x + nbx*(blockIdx.y + nby*blockIdx.z);
  int per = (nbx*nby*gridDim.z) >> 3;
  int id2 = (lin & 7)*per + (lin >> 3);
  int bx = id2 % nbx; int rem = id2 / nbx;
  int by = rem % nby; int g  = rem / nby;

  const int trow0 = bx * 128, ncol0 = by * 192;
  const int ne = (ec > g) ? ((ec - 1 - g) >> 2) + 1 : 0;

  f32x4 oacc[4][6];
  #pragma unroll
  for (int i = 0; i < 4; ++i)
    #pragma unroll
    for (int j = 0; j < 6; ++j) oacc[i][j] = (f32x4){0.f,0.f,0.f,0.f};

  auto sA = [&](const unsigned short* ap, int kt, int buf, int i){
    int task = i*256 + t, row = task >> 3, ch = task & 7, sch = ch ^ (row & 7);
    gload_lds16(ap + (size_t)(trow0 + row)*D + kt*64 + sch*8, &As[buf][task*8]);
  };
  auto sB = [&](const unsigned short* wd, int kt, int buf, int j){
    int task = j*256 + t, row = task >> 3, ch = task & 7, sch = ch ^ (row & 7);
    gload_lds16(wd + (size_t)(ncol0 + row)*D + kt*64 + sch*8, &Bs[buf][task*8]);
  };
  auto readAf = [&](bf16x8* af, int cur, int kk){
    #pragma unroll
    for (int mi = 0; mi < 4; ++mi){
      int row = wm*64 + mi*16 + (lane & 15);
      int pc  = (kk*4 + (lane>>4)) ^ (row & 7);
      af[mi] = *(const bf16x8*)&As[cur][row*64 + pc*8];
    }
  };
  auto readF3 = [&](bf16x8* fr, int cur, int kk, int nh){
    #pragma unroll
    for (int q = 0; q < 3; ++q){
      int row = wn*96 + (nh*3 + q)*16 + (lane & 15);
      int pc  = (kk*4 + (lane>>4)) ^ (row & 7);
      fr[q] = *(const bf16x8*)&Bs[cur][row*64 + pc*8];
    }
  };

  if (ne > 0){
    const unsigned short* ap0 = inter + (size_t)g * T * D;
    const unsigned short* wd0 = wdT + (size_t)g * H * D;
    #pragma unroll
    for (int i = 0; i < 4; ++i) sA(ap0, 0, 0, i);
    #pragma unroll
    for (int j = 0; j < 6; ++j) sB(wd0, 0, 0, j);   // 10 in flight

    int gkt = 0;
    for (int ei = 0; ei < ne; ++ei){
      const int ee = g + ei*4;
      const int e  = e0 + ee;
      f32x4 acc[4][6];
      #pragma unroll
      for (int i = 0; i < 4; ++i)
        #pragma unroll
        for (int j = 0; j < 6; ++j) acc[i][j] = (f32x4){0.f,0.f,0.f,0.f};

      for (int kt = 0; kt < NKT; ++kt, ++gkt){
        int cur = gkt & 1, nxt = cur ^ 1;
        int eeN, ktN;
        if (kt+1 < NKT)      { eeN = ee;     ktN = kt+1; }
        else if (ei+1 < ne)  { eeN = ee + 4; ktN = 0;    }
        else                 { eeN = ee;     ktN = kt;   }
        const unsigned short* apN = inter + (size_t)eeN * T * D;
        const unsigned short* wdN = wdT + (size_t)eeN * H * D;
        bf16x8 af[4], fr[3];
        // ---- P0: A0-2; wait; af0 x fb0(ni0-2)
        sA(apN, ktN, nxt, 0); sA(apN, ktN, nxt, 1); sA(apN, ktN, nxt, 2);
        asm volatile("s_waitcnt vmcnt(3)" ::: "memory");
        SCHED_FENCE(); SBAR(); SCHED_FENCE();
        readAf(af, cur, 0); readF3(fr, cur, 0, 0);
        LGK0(); SCHED_FENCE();
        PRIO1();
        #pragma unroll
        for (int q = 0; q < 3; ++q)
          #pragma unroll
          for (int mi = 0; mi < 4; ++mi)
            acc[mi][q] = MFMA_BF16(af[mi], fr[q], acc[mi][q]);
        PRIO0(); SBAR();
        // ---- P1: A3,B0,B1; af0 x fb0(ni3-5)
        sA(apN, ktN, nxt, 3); sB(wdN, ktN, nxt, 0); sB(wdN, ktN, nxt, 1);
        readF3(fr, cur, 0, 1);
        LGK0(); SCHED_FENCE();
        PRIO1();
        #pragma unroll
        for (int q = 0; q < 3; ++q)
          #pragma unroll
          for (int mi = 0; mi < 4; ++mi)
            acc[mi][3+q] = MFMA_BF16(af[mi], fr[q], acc[mi][3+q]);
        PRIO0(); SBAR();
        // ---- P2: B2,B3,B4; af1 x fb1(ni0-2)
        sB(wdN, ktN, nxt, 2); sB(wdN, ktN, nxt, 3); sB(wdN, ktN, nxt, 4);
        readAf(af, cur, 1); readF3(fr, cur, 1, 0);
        LGK0(); SCHED_FENCE();
        PRIO1();
        #pragma unroll
        for (int q = 0; q < 3; ++q)
          #pragma unroll
          for (int mi = 0; mi < 4; ++mi)
            acc[mi][q] = MFMA_BF16(af[mi], fr[q], acc[mi][q]);
        PRIO0(); SBAR();
        // ---- P3: B5; af1 x fb1(ni3-5)
        sB(wdN, ktN, nxt, 5);
        readF3(fr, cur, 1, 1);
        LGK0(); SCHED_FENCE();
        PRIO1();
        #pragma unroll
        for (int q = 0; q < 3; ++q)
          #pragma unroll
          for (int mi = 0; mi < 4; ++mi)
            acc[mi][3+q] = MFMA_BF16(af[mi], fr[q], acc[mi][3+q]);
        PRIO0(); SBAR();
      }

      // fold expert: bias + routing weight
      const float* bdp = bd + (size_t)e * H;
      #pragma unroll
      for (int ni = 0; ni < 6; ++ni){
        int h = ncol0 + wn*96 + ni*16 + (lane & 15);
        float bdv = bdp[h];
        #pragma unroll
        for (int mi = 0; mi < 4; ++mi){
          #pragma unroll
          for (int r = 0; r < 4; ++r){
            int trw = trow0 + wm*64 + mi*16 + (lane >> 4)*4 + r;
            float rv = rw[trw*E + e];
            oacc[mi][ni][r] += rv * (acc[mi][ni][r] + bdv);
          }
        }
      }
    }
    asm volatile("s_waitcnt vmcnt(0)" ::: "memory");
  }

  float* pp = pout + (size_t)g * T * H;
  const int accum = (e0 != 0);
  #pragma unroll
  for (int ni = 0; ni < 6; ++ni){
    int h = ncol0 + wn*96 + ni*16 + (lane & 15);
    #pragma unroll
    for (int mi = 0; mi < 4; ++mi){
      #pragma unroll
      for (int r = 0; r < 4; ++r){
        int trw = trow0 + wm*64 + mi*16 + (lane >> 4)*4 + r;
        size_t oi = (size_t)trw * H + h;
        float v = oacc[mi][ni][r];
        if (accum) v += pp[oi];
        pp[oi] = v;
      }
    }
  }
}

extern "C" void kernel_launch(void* const* d_in, const int* in_sizes, int n_in,
                              void* d_out, int out_size, void* d_ws, size_t ws_size,
                              hipStream_t stream) {
  const float* hs  = (const float*)d_in[0];
  const float* rwt = (const float*)d_in[1];
  const float* Wg  = (const float*)d_in[2];
  const float* bg  = (const float*)d_in[3];
  const float* Wu  = (const float*)d_in[4];
  const float* bu  = (const float*)d_in[5];
  const float* Wd  = (const float*)d_in[6];
  const float* bd  = (const float*)d_in[7];
  float* out = (float*)d_out;

  const size_t xbytes = (size_t)T * H * 2;          // 11.8 MB
  const size_t poutB  = (size_t)NG * T * H * 4;     // 94.4 MB
  const size_t interB = (size_t)T * D * 2;          // 11.8 MB / expert
  const size_t wB     = (size_t)H * D * 2;          // 16.6 MB / expert / matrix
  const size_t perE   = interB + 2*wB;              // ~45 MB / expert

  long long avail = (long long)ws_size - (long long)(xbytes + poutB);
  int EC = (int)(avail / (long long)perE);
  if (EC < 1) EC = 1;
  if (EC > E) EC = E;

  unsigned short* xb    = (unsigned short*)d_ws;
  float*          pout  = (float*)((char*)d_ws + xbytes);
  unsigned short* inter = (unsigned short*)((char*)d_ws + xbytes + poutB);
  unsigned short* wgT   = (unsigned short*)((char*)d_ws + xbytes + poutB + (size_t)EC*interB);
  unsigned short* wuT   = wgT + (size_t)EC * H * D;
  unsigned short* wdT   = wgT;   // aliases wgT (stream-serialized reuse)

  cvt_kernel<<<(T*H/8 + 255)/256, 256, 0, stream>>>(hs, xb, T*H/8);

  for (int e0 = 0; e0 < E; e0 += EC){
    int ec = (E - e0 < EC) ? (E - e0) : EC;
    tcvt_kernel<<<dim3(45,45,ec), 256, 0, stream>>>(Wg + (size_t)e0*H*D, wgT);
    tcvt_kernel<<<dim3(45,45,ec), 256, 0, stream>>>(Wu + (size_t)e0*H*D, wuT);
    gateup_kernel<<<dim3(T/128, D/96, ec), 256, 0, stream>>>(xb, wgT, bg, wuT, bu, inter, e0);
    tcvt_kernel<<<dim3(45,45,ec), 256, 0, stream>>>(Wd + (size_t)e0*D*H, wgT);
    down_kernel<<<dim3(T/128, H/192, NG), 256, 0, stream>>>(inter, wdT, bd, rwt, pout, e0, ec);
  }
  reduce_kernel<<<(T*H/4 + 255)/256, 256, 0, stream>>>(pout, out, T*H/4);
}

// Round 9
// 2174.515 us; speedup vs baseline: 2.0446x; 1.6266x over previous
//
#include <hip/hip_runtime.h>
#include <cstdint>

// GptOssExpertsLinear: E=16, H=D=2880, T=2048.
// out[t,h] = sum_e rw[t,e] * ( act(x@Wg[e]+bg, x@Wu[e]+bu) @ Wd[e] + bd )
// R9: gateup = m201-class 256x256x64 8-wave kernel, 4 phases/K-tile x
// 2-K-tile unrolled iter, ds_reads issued BEFORE barrier, 1 half-tile staged
// per phase via global_load_lds, counted vmcnt(6) at phase end (never 0).
// Quarter-interleaved LDS layout makes staged halves exactly the freed
// regions. Paired gate|up weight layout (32-col blocks), zero-padded N=3072.
// down kernel = R5 verbatim (proven). tcvt gains pairing/pad modes.

#define ALPHA 1.702f
#define LIMIT 7.0f

static constexpr int E = 16;
static constexpr int H = 2880;
static constexpr int D = 2880;
static constexpr int T = 2048;
static constexpr int NKT = 45;       // K-steps of 64 (K=2880)
static constexpr int NG  = 4;        // down expert groups
static constexpr int DP  = 3072;     // padded D for gateup N
static constexpr int NPR = 2*DP;     // 6144 paired rows (gate|up)

typedef float        f32x4  __attribute__((ext_vector_type(4)));
typedef short        bf16x8 __attribute__((ext_vector_type(8)));

#define MFMA_BF16(a,b,c) __builtin_amdgcn_mfma_f32_16x16x32_bf16((a),(b),(c),0,0,0)
#define SBAR()        __builtin_amdgcn_s_barrier()
#define SCHED_FENCE() __builtin_amdgcn_sched_barrier(0)
#define PRIO1()       __builtin_amdgcn_s_setprio(1)
#define PRIO0()       __builtin_amdgcn_s_setprio(0)
#define LGK0()        asm volatile("s_waitcnt lgkmcnt(0)" ::: "memory")
#define VMC6()        asm volatile("s_waitcnt vmcnt(6)" ::: "memory")

__device__ __forceinline__ unsigned short f2bf(float f){
  unsigned u = __builtin_bit_cast(unsigned, f);
  u += 0x7fffu + ((u >> 16) & 1u);
  return (unsigned short)(u >> 16);
}
__device__ __forceinline__ unsigned pack2(float a, float b){
  return (unsigned)f2bf(a) | ((unsigned)f2bf(b) << 16);
}

__device__ __forceinline__ void gload_lds16(const void* g, void* l){
  __builtin_amdgcn_global_load_lds((const __attribute__((address_space(1))) unsigned*)g,
                                   (__attribute__((address_space(3))) unsigned*)l,
                                   16, 0, 0);
}

// x fp32 -> bf16, 8 elems/thread
__global__ void cvt_kernel(const float* __restrict__ in, unsigned short* __restrict__ ob, int n8){
  int i = blockIdx.x * 256 + threadIdx.x;
  if (i < n8){
    float4 a = ((const float4*)in)[2*i];
    float4 b = ((const float4*)in)[2*i+1];
    uint4 o;
    o.x = pack2(a.x, a.y); o.y = pack2(a.z, a.w);
    o.z = pack2(b.x, b.y); o.w = pack2(b.z, b.w);
    ((uint4*)ob)[i] = o;
  }
}

// W fp32 -> bf16 transpose with row remap.
// mode 0: dst row = (c/32)*64 + c%32       (gate half of paired layout)
// mode 1: dst row = (c/32)*64 + c%32 + 32  (up half)
// mode 2: dst row = c                      (plain transpose, down weights)
// Pad blocks (c0 >= D, modes 0/1 only): write zeros.
__global__ __launch_bounds__(256) void tcvt_kernel(
    const float* __restrict__ src, unsigned short* __restrict__ dst,
    int mode, size_t dstStride)
{
  __shared__ unsigned short tl[64*72];
  const int t = threadIdx.x;
  const float* s = src + (size_t)blockIdx.z * H * D;
  unsigned short* o = dst + (size_t)blockIdx.z * dstStride;
  const int r0 = blockIdx.x * 64, c0 = blockIdx.y * 64;

  if (c0 < D){
    int rr = t >> 2;
    #pragma unroll
    for (int p = 0; p < 4; ++p){
      int cc = ((t & 3) + p*4) * 4;
      float4 v = *(const float4*)(s + (size_t)(r0 + rr)*D + c0 + cc);
      tl[(cc+0)*72 + rr] = f2bf(v.x);
      tl[(cc+1)*72 + rr] = f2bf(v.y);
      tl[(cc+2)*72 + rr] = f2bf(v.z);
      tl[(cc+3)*72 + rr] = f2bf(v.w);
    }
    __syncthreads();
    #pragma unroll
    for (int p = 0; p < 2; ++p){
      int task = p*256 + t;
      int cl = task >> 3, ch = task & 7;
      int c = c0 + cl;
      int rowp = (mode < 2) ? ((c >> 5)*64 + (c & 31) + mode*32) : c;
      bf16x8 v = *(const bf16x8*)&tl[cl*72 + ch*8];
      *(bf16x8*)(o + (size_t)rowp*H + r0 + ch*8) = v;
    }
  } else {
    #pragma unroll
    for (int p = 0; p < 2; ++p){
      int task = p*256 + t;
      int cl = task >> 3, ch = task & 7;
      int c = c0 + cl;
      int rowp = (c >> 5)*64 + (c & 31) + mode*32;
      bf16x8 z = (bf16x8){0,0,0,0,0,0,0,0};
      *(bf16x8*)(o + (size_t)rowp*H + r0 + ch*8) = z;
    }
  }
}

// sum the NG down partials -> out
__global__ void reduce_kernel(const float* __restrict__ p, float* __restrict__ out, int n4){
  int i = blockIdx.x * 256 + threadIdx.x;
  if (i < n4){
    f32x4 a = ((const f32x4*)p)[i];
    #pragma unroll
    for (int g = 1; g < NG; ++g)
      a += ((const f32x4*)(p + (size_t)g * T * H))[i];
    ((f32x4*)out)[i] = a;
  }
}

// ---------------- gate+up fused GEMM + activation (8-wave, 256x256) --------
// grid (8, 24, ec); 512 thr = 8 waves (2M x 4N); wave tile 128x64 paired.
__global__ __launch_bounds__(512, 2) void gateup_kernel(
    const unsigned short* __restrict__ xb,    // [T][H] bf16
    const unsigned short* __restrict__ wGU,   // [ec][6144][H] paired bf16
    const float* __restrict__ bg,
    const float* __restrict__ bu,
    unsigned short* __restrict__ inter,       // [ec][T][D] bf16
    int e0)
{
  __shared__ short As[2][256*64];   // 64KB (quarter-interleaved rows)
  __shared__ short Bs[2][256*64];   // 64KB => 128KB total

  const int t = threadIdx.x, lane = t & 63, wv = t >> 6;
  const int wm = wv >> 2, wn = wv & 3;

  int nbx = gridDim.x, nby = gridDim.y;
  int lin = blockIdx.x + nbx*(blockIdx.y + nby*blockIdx.z);
  int per = (nbx*nby*gridDim.z) >> 3;
  int id2 = (lin & 7)*per + (lin >> 3);
  int bx = id2 % nbx; int rem = id2 / nbx;
  int by = rem % nby; int ez = rem / nby;

  const int trow0 = bx*256, ncol0 = by*256;
  const int e = e0 + ez;
  const unsigned short* wg = wGU + (size_t)ez * NPR * H;

  f32x4 acc[8][4];
  #pragma unroll
  for (int i = 0; i < 8; ++i)
    #pragma unroll
    for (int j = 0; j < 4; ++j) acc[i][j] = (f32x4){0.f,0.f,0.f,0.f};

  // A halves: lo = logical quarters {0,2} (rows 0-63,128-191), hi = {1,3}.
  auto stageA = [&](int kt, int b, int h){
    #pragma unroll
    for (int r2 = 0; r2 < 2; ++r2){
      int task = r2*512 + t;
      int ps = task >> 3, ch = task & 7, sch = ch ^ (ps & 7);
      int lr = h*64 + (ps & 63) + ((ps >> 6) << 7);  // logical tile row
      gload_lds16(xb + (size_t)(trow0 + lr)*H + kt*64 + sch*8,
                  &As[b][h*8192 + task*8]);
    }
  };
  // B halves: lo = 32-blocks {0,2,4,6} (per-wave first 32 cols), hi = odd.
  auto stageB = [&](int kt, int b, int h){
    #pragma unroll
    for (int r2 = 0; r2 < 2; ++r2){
      int task = r2*512 + t;
      int ps = task >> 3, ch = task & 7, sch = ch ^ (ps & 7);
      int lr = h*32 + ((ps >> 5) << 6) + (ps & 31);
      gload_lds16(wg + (size_t)(ncol0 + lr)*H + kt*64 + sch*8,
                  &Bs[b][h*8192 + task*8]);
    }
  };

  bf16x8 af[4][2], bLo[2][2], bHi[2][2];
  auto readAh = [&](int b, int qa){
    #pragma unroll
    for (int mi = 0; mi < 4; ++mi){
      int r = wm*128 + qa*64 + mi*16 + (lane & 15);
      int q = r >> 6, qs = ((q & 1) << 1) | (q >> 1);
      int pr = qs*64 + (r & 63);
      #pragma unroll
      for (int kk = 0; kk < 2; ++kk){
        int pc = (kk*4 + (lane >> 4)) ^ (pr & 7);
        af[mi][kk] = *(const bf16x8*)&As[b][pr*64 + pc*8];
      }
    }
  };
  auto readBh = [&](bf16x8 (&bf)[2][2], int b, int hb){
    #pragma unroll
    for (int ni = 0; ni < 2; ++ni){
      int rB = wn*64 + hb*32 + ni*16 + (lane & 15);
      int pr = ((rB >> 5) & 1)*128 + (rB >> 6)*32 + (rB & 31);
      #pragma unroll
      for (int kk = 0; kk < 2; ++kk){
        int pc = (kk*4 + (lane >> 4)) ^ (pr & 7);
        bf[ni][kk] = *(const bf16x8*)&Bs[b][pr*64 + pc*8];
      }
    }
  };
  auto mfmaQ = [&](bf16x8 (&bf)[2][2], int qa, int hb){
    #pragma unroll
    for (int kk = 0; kk < 2; ++kk)
      #pragma unroll
      for (int ni = 0; ni < 2; ++ni)
        #pragma unroll
        for (int mi = 0; mi < 4; ++mi)
          acc[qa*4+mi][hb*2+ni] = MFMA_BF16(af[mi][kk], bf[ni][kk], acc[qa*4+mi][hb*2+ni]);
  };

  // prologue: 7 half-tiles (A1hi staged at first p1)
  stageA(0,0,0); stageB(0,0,0); stageB(0,0,1); stageA(0,0,1);
  stageA(1,1,0); stageB(1,1,0); stageB(1,1,1);
  asm volatile("s_waitcnt vmcnt(8)" ::: "memory");
  SBAR();

  for (int it = 0; it < 22; ++it){
    int kt = 2*it;
    int ktA = (kt+2 < NKT) ? kt+2 : NKT-1;
    int ktB = (kt+3 < NKT) ? kt+3 : NKT-1;
    // p1: Q1(kt) af_lo x B_lo ; stage A(kt+1)hi -> b1
    readAh(0, 0); readBh(bLo, 0, 0);
    stageA(kt+1, 1, 1);
    SCHED_FENCE(); SBAR(); LGK0(); SCHED_FENCE();
    PRIO1(); mfmaQ(bLo, 0, 0); PRIO0();
    VMC6(); SBAR();
    // p2: Q2(kt) af_lo x B_hi ; stage A(kt+2)lo -> b0
    readBh(bHi, 0, 1);
    stageA(ktA, 0, 0);
    SCHED_FENCE(); SBAR(); LGK0(); SCHED_FENCE();
    PRIO1(); mfmaQ(bHi, 0, 1); PRIO0();
    VMC6(); SBAR();
    // p3: Q3(kt) af_hi x B_hi ; stage B(kt+2)lo -> b0
    readAh(0, 1);
    stageB(ktA, 0, 0);
    SCHED_FENCE(); SBAR(); LGK0(); SCHED_FENCE();
    PRIO1(); mfmaQ(bHi, 1, 1); PRIO0();
    VMC6(); SBAR();
    // p4: Q4(kt) af_hi x B_lo (regs only) ; stage B(kt+2)hi -> b0
    stageB(ktA, 0, 1);
    SCHED_FENCE(); SBAR(); SCHED_FENCE();
    PRIO1(); mfmaQ(bLo, 1, 0); PRIO0();
    VMC6(); SBAR();
    // p5: Q1(kt+1) ; stage A(kt+2)hi -> b0
    readAh(1, 0); readBh(bLo, 1, 0);
    stageA(ktA, 0, 1);
    SCHED_FENCE(); SBAR(); LGK0(); SCHED_FENCE();
    PRIO1(); mfmaQ(bLo, 0, 0); PRIO0();
    VMC6(); SBAR();
    // p6: Q2(kt+1) ; stage A(kt+3)lo -> b1
    readBh(bHi, 1, 1);
    stageA(ktB, 1, 0);
    SCHED_FENCE(); SBAR(); LGK0(); SCHED_FENCE();
    PRIO1(); mfmaQ(bHi, 0, 1); PRIO0();
    VMC6(); SBAR();
    // p7: Q3(kt+1) ; stage B(kt+3)lo -> b1
    readAh(1, 1);
    stageB(ktB, 1, 0);
    SCHED_FENCE(); SBAR(); LGK0(); SCHED_FENCE();
    PRIO1(); mfmaQ(bHi, 1, 1); PRIO0();
    VMC6(); SBAR();
    // p8: Q4(kt+1) ; stage B(kt+3)hi -> b1
    stageB(ktB, 1, 1);
    SCHED_FENCE(); SBAR(); SCHED_FENCE();
    PRIO1(); mfmaQ(bLo, 1, 0); PRIO0();
    VMC6(); SBAR();
  }

  // tail: K-tile 44 from buf0
  asm volatile("s_waitcnt vmcnt(0)" ::: "memory");
  SBAR();
  readAh(0, 0); readBh(bLo, 0, 0); readBh(bHi, 0, 1);
  LGK0(); SCHED_FENCE();
  mfmaQ(bLo, 0, 0); mfmaQ(bHi, 0, 1);
  readAh(0, 1);
  LGK0(); SCHED_FENCE();
  mfmaQ(bHi, 1, 1); mfmaQ(bLo, 1, 0);

  // epilogue: gate ni g pairs with up ni g+2 (same d), mask pad d >= 2880
  const float* bgp = bg + (size_t)e * D;
  const float* bup = bu + (size_t)e * D;
  unsigned short* ip = inter + (size_t)ez * T * D;
  const int dbase = (by*4 + wn) * 32;
  #pragma unroll
  for (int g = 0; g < 2; ++g){
    int d0 = dbase + g*16;
    if (d0 < D){
      int d = d0 + (lane & 15);
      float bgv = bgp[d], buv = bup[d];
      #pragma unroll
      for (int mi = 0; mi < 8; ++mi){
        #pragma unroll
        for (int r = 0; r < 4; ++r){
          int trw = trow0 + wm*128 + mi*16 + (lane >> 4)*4 + r;
          float gv = acc[mi][g][r] + bgv;
          float uv = acc[mi][g+2][r] + buv;
          gv = fminf(gv, LIMIT);
          uv = fminf(fmaxf(uv, -LIMIT), LIMIT);
          float glu = gv / (1.f + __expf(-ALPHA * gv));
          ip[(size_t)trw * D + d] = f2bf((uv + 1.f) * glu);
        }
      }
    }
  }
}

// ---------------- down GEMM + routing-weighted accumulate (R5 verbatim) ----
// grid (16, 15, NG); tile 128x192; wave tile 64x96.
__global__ __launch_bounds__(256, 2) void down_kernel(
    const unsigned short* __restrict__ inter, // [ec][T][D] bf16
    const unsigned short* __restrict__ wdT,   // [ec][H][D] bf16 (n-major)
    const float* __restrict__ bd,
    const float* __restrict__ rw,             // [T][E]
    float* __restrict__ pout,                 // [NG][T][H] fp32 partials
    int e0, int ec)
{
  __shared__ short As[2][128*64];   // 32KB
  __shared__ short Bs[2][192*64];   // 48KB => 80KB, 2 blocks/CU

  const int t = threadIdx.x, lane = t & 63, wv = t >> 6;
  const int wm = wv >> 1, wn = wv & 1;

  int nbx = gridDim.x, nby = gridDim.y;
  int lin = blockIdx.x + nbx*(blockIdx.y + nby*blockIdx.z);
  int per = (nbx*nby*gridDim.z) >> 3;
  int id2 = (lin & 7)*per + (lin >> 3);
  int bx = id2 % nbx; int rem = id2 / nbx;
  int by = rem % nby; int g  = rem / nby;

  const int trow0 = bx * 128, ncol0 = by * 192;
  const int ne = (ec > g) ? ((ec - 1 - g) >> 2) + 1 : 0;

  f32x4 oacc[4][6];
  #pragma unroll
  for (int i = 0; i < 4; ++i)
    #pragma unroll
    for (int j = 0; j < 6; ++j) oacc[i][j] = (f32x4){0.f,0.f,0.f,0.f};

  auto stage = [&](int ee, int kt, int buf){
    const unsigned short* ap = inter + (size_t)ee * T * D;
    const unsigned short* wd = wdT + (size_t)ee * H * D;
    #pragma unroll
    for (int i = 0; i < 4; ++i){
      int task = i*256 + t, row = task >> 3, ch = task & 7, sch = ch ^ (row & 7);
      gload_lds16(ap + (size_t)(trow0 + row)*D + kt*64 + sch*8, &As[buf][task*8]);
    }
    #pragma unroll
    for (int j = 0; j < 6; ++j){
      int task = j*256 + t, row = task >> 3, ch = task & 7, sch = ch ^ (row & 7);
      gload_lds16(wd + (size_t)(ncol0 + row)*D + kt*64 + sch*8, &Bs[buf][task*8]);
    }
  };

  if (ne > 0){
    stage(g, 0, 0);   // 10 vmem

    int gkt = 0;
    for (int ei = 0; ei < ne; ++ei){
      const int ee = g + ei*4;
      const int e  = e0 + ee;
      f32x4 acc[4][6];
      #pragma unroll
      for (int i = 0; i < 4; ++i)
        #pragma unroll
        for (int j = 0; j < 6; ++j) acc[i][j] = (f32x4){0.f,0.f,0.f,0.f};

      for (int kt = 0; kt < NKT; ++kt, ++gkt){
        int cur = gkt & 1, nxt = cur ^ 1;
        int eeN, ktN;
        if (kt+1 < NKT)      { eeN = ee;     ktN = kt+1; }
        else if (ei+1 < ne)  { eeN = ee + 4; ktN = 0;    }
        else                 { eeN = ee;     ktN = kt;   }
        stage(eeN, ktN, nxt);
        asm volatile("s_waitcnt vmcnt(10)" ::: "memory");
        SCHED_FENCE(); SBAR(); SCHED_FENCE();
        #pragma unroll
        for (int kk = 0; kk < 2; ++kk){
          bf16x8 af2[4];
          #pragma unroll
          for (int mi = 0; mi < 4; ++mi){
            int row = wm*64 + mi*16 + (lane & 15);
            int pc  = (kk*4 + (lane>>4)) ^ (row & 7);
            af2[mi] = *(const bf16x8*)&As[cur][row*64 + pc*8];
          }
          bf16x8 fb[6];
          #pragma unroll
          for (int ni = 0; ni < 6; ++ni){
            int row = wn*96 + ni*16 + (lane & 15);
            int pc  = (kk*4 + (lane>>4)) ^ (row & 7);
            fb[ni] = *(const bf16x8*)&Bs[cur][row*64 + pc*8];
          }
          #pragma unroll
          for (int ni = 0; ni < 6; ++ni)
            #pragma unroll
            for (int mi = 0; mi < 4; ++mi)
              acc[mi][ni] = MFMA_BF16(af2[mi], fb[ni], acc[mi][ni]);
        }
        SBAR();
      }

      const float* bdp = bd + (size_t)e * H;
      #pragma unroll
      for (int ni = 0; ni < 6; ++ni){
        int h = ncol0 + wn*96 + ni*16 + (lane & 15);
        float bdv = bdp[h];
        #pragma unroll
        for (int mi = 0; mi < 4; ++mi){
          #pragma unroll
          for (int r = 0; r < 4; ++r){
            int trw = trow0 + wm*64 + mi*16 + (lane >> 4)*4 + r;
            float rv = rw[trw*E + e];
            oacc[mi][ni][r] += rv * (acc[mi][ni][r] + bdv);
          }
        }
      }
    }
    asm volatile("s_waitcnt vmcnt(0)" ::: "memory");
  }

  float* pp = pout + (size_t)g * T * H;
  const int accum = (e0 != 0);
  #pragma unroll
  for (int ni = 0; ni < 6; ++ni){
    int h = ncol0 + wn*96 + ni*16 + (lane & 15);
    #pragma unroll
    for (int mi = 0; mi < 4; ++mi){
      #pragma unroll
      for (int r = 0; r < 4; ++r){
        int trw = trow0 + wm*64 + mi*16 + (lane >> 4)*4 + r;
        size_t oi = (size_t)trw * H + h;
        float v = oacc[mi][ni][r];
        if (accum) v += pp[oi];
        pp[oi] = v;
      }
    }
  }
}

extern "C" void kernel_launch(void* const* d_in, const int* in_sizes, int n_in,
                              void* d_out, int out_size, void* d_ws, size_t ws_size,
                              hipStream_t stream) {
  const float* hs  = (const float*)d_in[0];
  const float* rwt = (const float*)d_in[1];
  const float* Wg  = (const float*)d_in[2];
  const float* bg  = (const float*)d_in[3];
  const float* Wu  = (const float*)d_in[4];
  const float* bu  = (const float*)d_in[5];
  const float* Wd  = (const float*)d_in[6];
  const float* bd  = (const float*)d_in[7];
  float* out = (float*)d_out;

  const size_t xbytes = (size_t)T * H * 2;          // 11.8 MB
  const size_t poutB  = (size_t)NG * T * H * 4;     // 94.4 MB
  const size_t interB = (size_t)T * D * 2;          // 11.8 MB / expert
  const size_t guB    = (size_t)NPR * H * 2;        // 35.4 MB / expert (paired+pad)
  const size_t perE   = interB + guB;               // ~47 MB / expert

  long long avail = (long long)ws_size - (long long)(xbytes + poutB);
  int EC = (int)(avail / (long long)perE);
  if (EC < 1) EC = 1;
  if (EC > E) EC = E;

  unsigned short* xb    = (unsigned short*)d_ws;
  float*          pout  = (float*)((char*)d_ws + xbytes);
  unsigned short* inter = (unsigned short*)((char*)d_ws + xbytes + poutB);
  unsigned short* wGU   = (unsigned short*)((char*)d_ws + xbytes + poutB + (size_t)EC*interB);
  unsigned short* wdT   = wGU;   // aliases wGU (stream-serialized reuse)

  cvt_kernel<<<(T*H/8 + 255)/256, 256, 0, stream>>>(hs, xb, T*H/8);

  for (int e0 = 0; e0 < E; e0 += EC){
    int ec = (E - e0 < EC) ? (E - e0) : EC;
    tcvt_kernel<<<dim3(45,48,ec), 256, 0, stream>>>(Wg + (size_t)e0*H*D, wGU, 0, (size_t)NPR*H);
    tcvt_kernel<<<dim3(45,48,ec), 256, 0, stream>>>(Wu + (size_t)e0*H*D, wGU, 1, (size_t)NPR*H);
    gateup_kernel<<<dim3(8, 24, ec), 512, 0, stream>>>(xb, wGU, bg, bu, inter, e0);
    tcvt_kernel<<<dim3(45,45,ec), 256, 0, stream>>>(Wd + (size_t)e0*D*H, wdT, 2, (size_t)D*H);
    down_kernel<<<dim3(16, 15, NG), 256, 0, stream>>>(inter, wdT, bd, rwt, pout, e0, ec);
  }
  reduce_kernel<<<(T*H/4 + 255)/256, 256, 0, stream>>>(pout, out, T*H/4);
}

// Round 10
// 2150.655 us; speedup vs baseline: 2.0673x; 1.0111x over previous
//
#include <hip/hip_runtime.h>
#include <cstdint>

// GptOssExpertsLinear: E=16, H=D=2880, T=2048.
// out[t,h] = sum_e rw[t,e] * ( act(x@Wg[e]+bg, x@Wu[e]+bu) @ Wd[e] + bd )
// R10: 2-chunk expert pipeline. Chunk c_i's down kernel hosts "strip" tcvt
// blocks (appended to its grid) that convert chunk c_{i+1}'s weights
// concurrently, using the free co-residency slots of down's 2nd round.
// Only chunk 0's conversion is exposed. gateup = R9 8-phase 256x256 (990 TF),
// down gemm = R5 structure (857 TF), both unchanged.

#define ALPHA 1.702f
#define LIMIT 7.0f

static constexpr int E = 16;
static constexpr int H = 2880;
static constexpr int D = 2880;
static constexpr int T = 2048;
static constexpr int NKT = 45;       // K-steps of 64 (K=2880)
static constexpr int NG  = 4;        // down expert groups
static constexpr int DP  = 3072;     // padded D for gateup N
static constexpr int NPR = 2*DP;     // 6144 paired rows (gate|up)
static constexpr int NBGEMM = 16*15*NG;  // 960 down gemm blocks

typedef float        f32x4  __attribute__((ext_vector_type(4)));
typedef short        bf16x8 __attribute__((ext_vector_type(8)));

#define MFMA_BF16(a,b,c) __builtin_amdgcn_mfma_f32_16x16x32_bf16((a),(b),(c),0,0,0)
#define SBAR()        __builtin_amdgcn_s_barrier()
#define SCHED_FENCE() __builtin_amdgcn_sched_barrier(0)
#define PRIO1()       __builtin_amdgcn_s_setprio(1)
#define PRIO0()       __builtin_amdgcn_s_setprio(0)
#define LGK0()        asm volatile("s_waitcnt lgkmcnt(0)" ::: "memory")
#define VMC6()        asm volatile("s_waitcnt vmcnt(6)" ::: "memory")

__device__ __forceinline__ unsigned short f2bf(float f){
  unsigned u = __builtin_bit_cast(unsigned, f);
  u += 0x7fffu + ((u >> 16) & 1u);
  return (unsigned short)(u >> 16);
}
__device__ __forceinline__ unsigned pack2(float a, float b){
  return (unsigned)f2bf(a) | ((unsigned)f2bf(b) << 16);
}

__device__ __forceinline__ void gload_lds16(const void* g, void* l){
  __builtin_amdgcn_global_load_lds((const __attribute__((address_space(1))) unsigned*)g,
                                   (__attribute__((address_space(3))) unsigned*)l,
                                   16, 0, 0);
}

// x fp32 -> bf16, 8 elems/thread
__global__ void cvt_kernel(const float* __restrict__ in, unsigned short* __restrict__ ob, int n8){
  int i = blockIdx.x * 256 + threadIdx.x;
  if (i < n8){
    float4 a = ((const float4*)in)[2*i];
    float4 b = ((const float4*)in)[2*i+1];
    uint4 o;
    o.x = pack2(a.x, a.y); o.y = pack2(a.z, a.w);
    o.z = pack2(b.x, b.y); o.w = pack2(b.z, b.w);
    ((uint4*)ob)[i] = o;
  }
}

// W fp32 -> bf16 transpose with row remap (exposed path, chunk 0 only).
// mode 0/1: paired gate|up rows (32-col blocks); mode 2: plain transpose.
__global__ __launch_bounds__(256) void tcvt_kernel(
    const float* __restrict__ src, unsigned short* __restrict__ dst,
    int mode, size_t dstStride)
{
  __shared__ unsigned short tl[64*72];
  const int t = threadIdx.x;
  const float* s = src + (size_t)blockIdx.z * H * D;
  unsigned short* o = dst + (size_t)blockIdx.z * dstStride;
  const int r0 = blockIdx.x * 64, c0 = blockIdx.y * 64;

  if (c0 < D){
    int rr = t >> 2;
    #pragma unroll
    for (int p = 0; p < 4; ++p){
      int cc = ((t & 3) + p*4) * 4;
      float4 v = *(const float4*)(s + (size_t)(r0 + rr)*D + c0 + cc);
      tl[(cc+0)*72 + rr] = f2bf(v.x);
      tl[(cc+1)*72 + rr] = f2bf(v.y);
      tl[(cc+2)*72 + rr] = f2bf(v.z);
      tl[(cc+3)*72 + rr] = f2bf(v.w);
    }
    __syncthreads();
    #pragma unroll
    for (int p = 0; p < 2; ++p){
      int task = p*256 + t;
      int cl = task >> 3, ch = task & 7;
      int c = c0 + cl;
      int rowp = (mode < 2) ? ((c >> 5)*64 + (c & 31) + mode*32) : c;
      bf16x8 v = *(const bf16x8*)&tl[cl*72 + ch*8];
      *(bf16x8*)(o + (size_t)rowp*H + r0 + ch*8) = v;
    }
  } else {
    #pragma unroll
    for (int p = 0; p < 2; ++p){
      int task = p*256 + t;
      int cl = task >> 3, ch = task & 7;
      int c = c0 + cl;
      int rowp = (c >> 5)*64 + (c & 31) + mode*32;
      bf16x8 z = (bf16x8){0,0,0,0,0,0,0,0};
      *(bf16x8*)(o + (size_t)rowp*H + r0 + ch*8) = z;
    }
  }
}

// sum the NG down partials -> out
__global__ void reduce_kernel(const float* __restrict__ p, float* __restrict__ out, int n4){
  int i = blockIdx.x * 256 + threadIdx.x;
  if (i < n4){
    f32x4 a = ((const f32x4*)p)[i];
    #pragma unroll
    for (int g = 1; g < NG; ++g)
      a += ((const f32x4*)(p + (size_t)g * T * H))[i];
    ((f32x4*)out)[i] = a;
  }
}

// ---------------- gate+up fused GEMM + activation (R9, unchanged) ----------
// grid (8, 24, ec); 512 thr = 8 waves (2M x 4N); wave tile 128x64 paired.
__global__ __launch_bounds__(512, 2) void gateup_kernel(
    const unsigned short* __restrict__ xb,    // [T][H] bf16
    const unsigned short* __restrict__ wGU,   // [ec][6144][H] paired bf16
    const float* __restrict__ bg,
    const float* __restrict__ bu,
    unsigned short* __restrict__ inter,       // [ec][T][D] bf16
    int e0)
{
  __shared__ short As[2][256*64];   // 64KB (quarter-interleaved rows)
  __shared__ short Bs[2][256*64];   // 64KB => 128KB total

  const int t = threadIdx.x, lane = t & 63, wv = t >> 6;
  const int wm = wv >> 2, wn = wv & 3;

  int nbx = gridDim.x, nby = gridDim.y;
  int lin = blockIdx.x + nbx*(blockIdx.y + nby*blockIdx.z);
  int per = (nbx*nby*gridDim.z) >> 3;
  int id2 = (lin & 7)*per + (lin >> 3);
  int bx = id2 % nbx; int rem = id2 / nbx;
  int by = rem % nby; int ez = rem / nby;

  const int trow0 = bx*256;
  const int e = e0 + ez;
  const unsigned short* wg = wGU + (size_t)ez * NPR * H;
  const int ncol0 = by*256;

  f32x4 acc[8][4];
  #pragma unroll
  for (int i = 0; i < 8; ++i)
    #pragma unroll
    for (int j = 0; j < 4; ++j) acc[i][j] = (f32x4){0.f,0.f,0.f,0.f};

  auto stageA = [&](int kt, int b, int h){
    #pragma unroll
    for (int r2 = 0; r2 < 2; ++r2){
      int task = r2*512 + t;
      int ps = task >> 3, ch = task & 7, sch = ch ^ (ps & 7);
      int lr = h*64 + (ps & 63) + ((ps >> 6) << 7);
      gload_lds16(xb + (size_t)(trow0 + lr)*H + kt*64 + sch*8,
                  &As[b][h*8192 + task*8]);
    }
  };
  auto stageB = [&](int kt, int b, int h){
    #pragma unroll
    for (int r2 = 0; r2 < 2; ++r2){
      int task = r2*512 + t;
      int ps = task >> 3, ch = task & 7, sch = ch ^ (ps & 7);
      int lr = h*32 + ((ps >> 5) << 6) + (ps & 31);
      gload_lds16(wg + (size_t)(ncol0 + lr)*H + kt*64 + sch*8,
                  &Bs[b][h*8192 + task*8]);
    }
  };

  bf16x8 af[4][2], bLo[2][2], bHi[2][2];
  auto readAh = [&](int b, int qa){
    #pragma unroll
    for (int mi = 0; mi < 4; ++mi){
      int r = wm*128 + qa*64 + mi*16 + (lane & 15);
      int q = r >> 6, qs = ((q & 1) << 1) | (q >> 1);
      int pr = qs*64 + (r & 63);
      #pragma unroll
      for (int kk = 0; kk < 2; ++kk){
        int pc = (kk*4 + (lane >> 4)) ^ (pr & 7);
        af[mi][kk] = *(const bf16x8*)&As[b][pr*64 + pc*8];
      }
    }
  };
  auto readBh = [&](bf16x8 (&bf)[2][2], int b, int hb){
    #pragma unroll
    for (int ni = 0; ni < 2; ++ni){
      int rB = wn*64 + hb*32 + ni*16 + (lane & 15);
      int pr = ((rB >> 5) & 1)*128 + (rB >> 6)*32 + (rB & 31);
      #pragma unroll
      for (int kk = 0; kk < 2; ++kk){
        int pc = (kk*4 + (lane >> 4)) ^ (pr & 7);
        bf[ni][kk] = *(const bf16x8*)&Bs[b][pr*64 + pc*8];
      }
    }
  };
  auto mfmaQ = [&](bf16x8 (&bf)[2][2], int qa, int hb){
    #pragma unroll
    for (int kk = 0; kk < 2; ++kk)
      #pragma unroll
      for (int ni = 0; ni < 2; ++ni)
        #pragma unroll
        for (int mi = 0; mi < 4; ++mi)
          acc[qa*4+mi][hb*2+ni] = MFMA_BF16(af[mi][kk], bf[ni][kk], acc[qa*4+mi][hb*2+ni]);
  };

  stageA(0,0,0); stageB(0,0,0); stageB(0,0,1); stageA(0,0,1);
  stageA(1,1,0); stageB(1,1,0); stageB(1,1,1);
  asm volatile("s_waitcnt vmcnt(8)" ::: "memory");
  SBAR();

  for (int it = 0; it < 22; ++it){
    int kt = 2*it;
    int ktA = (kt+2 < NKT) ? kt+2 : NKT-1;
    int ktB = (kt+3 < NKT) ? kt+3 : NKT-1;
    readAh(0, 0); readBh(bLo, 0, 0);
    stageA(kt+1, 1, 1);
    SCHED_FENCE(); SBAR(); LGK0(); SCHED_FENCE();
    PRIO1(); mfmaQ(bLo, 0, 0); PRIO0();
    VMC6(); SBAR();
    readBh(bHi, 0, 1);
    stageA(ktA, 0, 0);
    SCHED_FENCE(); SBAR(); LGK0(); SCHED_FENCE();
    PRIO1(); mfmaQ(bHi, 0, 1); PRIO0();
    VMC6(); SBAR();
    readAh(0, 1);
    stageB(ktA, 0, 0);
    SCHED_FENCE(); SBAR(); LGK0(); SCHED_FENCE();
    PRIO1(); mfmaQ(bHi, 1, 1); PRIO0();
    VMC6(); SBAR();
    stageB(ktA, 0, 1);
    SCHED_FENCE(); SBAR(); SCHED_FENCE();
    PRIO1(); mfmaQ(bLo, 1, 0); PRIO0();
    VMC6(); SBAR();
    readAh(1, 0); readBh(bLo, 1, 0);
    stageA(ktA, 0, 1);
    SCHED_FENCE(); SBAR(); LGK0(); SCHED_FENCE();
    PRIO1(); mfmaQ(bLo, 0, 0); PRIO0();
    VMC6(); SBAR();
    readBh(bHi, 1, 1);
    stageA(ktB, 1, 0);
    SCHED_FENCE(); SBAR(); LGK0(); SCHED_FENCE();
    PRIO1(); mfmaQ(bHi, 0, 1); PRIO0();
    VMC6(); SBAR();
    readAh(1, 1);
    stageB(ktB, 1, 0);
    SCHED_FENCE(); SBAR(); LGK0(); SCHED_FENCE();
    PRIO1(); mfmaQ(bHi, 1, 1); PRIO0();
    VMC6(); SBAR();
    stageB(ktB, 1, 1);
    SCHED_FENCE(); SBAR(); SCHED_FENCE();
    PRIO1(); mfmaQ(bLo, 1, 0); PRIO0();
    VMC6(); SBAR();
  }

  asm volatile("s_waitcnt vmcnt(0)" ::: "memory");
  SBAR();
  readAh(0, 0); readBh(bLo, 0, 0); readBh(bHi, 0, 1);
  LGK0(); SCHED_FENCE();
  mfmaQ(bLo, 0, 0); mfmaQ(bHi, 0, 1);
  readAh(0, 1);
  LGK0(); SCHED_FENCE();
  mfmaQ(bHi, 1, 1); mfmaQ(bLo, 1, 0);

  const float* bgp = bg + (size_t)e * D;
  const float* bup = bu + (size_t)e * D;
  unsigned short* ip = inter + (size_t)ez * T * D;
  const int dbase = (by*4 + wn) * 32;
  #pragma unroll
  for (int g = 0; g < 2; ++g){
    int d0 = dbase + g*16;
    if (d0 < D){
      int d = d0 + (lane & 15);
      float bgv = bgp[d], buv = bup[d];
      #pragma unroll
      for (int mi = 0; mi < 8; ++mi){
        #pragma unroll
        for (int r = 0; r < 4; ++r){
          int trw = trow0 + wm*128 + mi*16 + (lane >> 4)*4 + r;
          float gv = acc[mi][g][r] + bgv;
          float uv = acc[mi][g+2][r] + buv;
          gv = fminf(gv, LIMIT);
          uv = fminf(fmaxf(uv, -LIMIT), LIMIT);
          float glu = gv / (1.f + __expf(-ALPHA * gv));
          ip[(size_t)trw * D + d] = f2bf((uv + 1.f) * glu);
        }
      }
    }
  }
}

// ---------------- down GEMM (R5 structure) + folded strip-tcvt tail --------
// grid 1D: [0,960) = gemm blocks (16x15xNG); [960,960+3*45*ecN) = strip
// blocks converting next chunk's Wg/Wu/Wd. LDS overlaid in one 80KB carve.
__global__ __launch_bounds__(256, 2) void down_kernel(
    const unsigned short* __restrict__ inter, // [ec][T][D] bf16
    const unsigned short* __restrict__ wdT,   // [ec][H][D] bf16 (n-major)
    const float* __restrict__ bd,
    const float* __restrict__ rw,             // [T][E]
    float* __restrict__ pout,                 // [NG][T][H] fp32 partials
    int e0, int ec,
    const float* __restrict__ Wg, const float* __restrict__ Wu,
    const float* __restrict__ Wd,
    unsigned short* __restrict__ wGUn,        // next chunk paired dst
    unsigned short* __restrict__ wdTn,        // next chunk plain dst
    int e0N, int ecN)
{
  __shared__ __attribute__((aligned(16))) unsigned char ldsb[81920];
  auto As = (short(*)[128*64])(ldsb);            // 2 x 16KB
  auto Bs = (short(*)[192*64])(ldsb + 32768);    // 2 x 24KB
  unsigned short* tl = (unsigned short*)ldsb;    // strip path: 9.2KB reuse

  const int t = threadIdx.x;
  const int flat = blockIdx.x;

  if (flat >= NBGEMM){
    // ---------- strip tcvt for next chunk ----------
    int sid = flat - NBGEMM;
    int perm = 45 * ecN;
    int mat = sid / perm, rem2 = sid % perm;
    int ez = rem2 / 45, cs = rem2 % 45;
    const float* src; unsigned short* dst; int mode;
    if (mat == 0){ src = Wg + (size_t)(e0N+ez)*H*D; dst = wGUn + (size_t)ez*NPR*H; mode = 0; }
    else if (mat == 1){ src = Wu + (size_t)(e0N+ez)*H*D; dst = wGUn + (size_t)ez*NPR*H; mode = 1; }
    else { src = Wd + (size_t)(e0N+ez)*H*D; dst = wdTn + (size_t)ez*D*H; mode = 2; }
    const int c0 = cs*64;
    const int rr = t >> 2;
    float4 pv[4];
    auto ld = [&](int r0){
      #pragma unroll
      for (int p = 0; p < 4; ++p){
        int cc = ((t & 3) + p*4) * 4;
        pv[p] = *(const float4*)(src + (size_t)(r0 + rr)*D + c0 + cc);
      }
    };
    ld(0);
    for (int r0 = 0; r0 < H; r0 += 64){
      float4 cv[4];
      #pragma unroll
      for (int p = 0; p < 4; ++p) cv[p] = pv[p];
      if (r0 + 64 < H) ld(r0 + 64);       // prefetch overlaps transpose+store
      #pragma unroll
      for (int p = 0; p < 4; ++p){
        int cc = ((t & 3) + p*4) * 4;
        tl[(cc+0)*72 + rr] = f2bf(cv[p].x);
        tl[(cc+1)*72 + rr] = f2bf(cv[p].y);
        tl[(cc+2)*72 + rr] = f2bf(cv[p].z);
        tl[(cc+3)*72 + rr] = f2bf(cv[p].w);
      }
      __syncthreads();
      #pragma unroll
      for (int p = 0; p < 2; ++p){
        int task = p*256 + t;
        int cl = task >> 3, ch = task & 7;
        int c = c0 + cl;
        int rowp = (mode < 2) ? ((c >> 5)*64 + (c & 31) + mode*32) : c;
        bf16x8 v = *(const bf16x8*)&tl[cl*72 + ch*8];
        *(bf16x8*)(dst + (size_t)rowp*H + r0 + ch*8) = v;
      }
      __syncthreads();
    }
    return;
  }

  // ---------- gemm path (R5 structure) ----------
  const int lane = t & 63, wv = t >> 6;
  const int wm = wv >> 1, wn = wv & 1;

  int perb = NBGEMM >> 3;                 // 120
  int id2 = (flat & 7)*perb + (flat >> 3);
  int bx = id2 % 16; int rem = id2 / 16;
  int by = rem % 15; int g = rem / 15;

  const int trow0 = bx * 128, ncol0 = by * 192;
  const int ne = (ec > g) ? ((ec - 1 - g) >> 2) + 1 : 0;

  f32x4 oacc[4][6];
  #pragma unroll
  for (int i = 0; i < 4; ++i)
    #pragma unroll
    for (int j = 0; j < 6; ++j) oacc[i][j] = (f32x4){0.f,0.f,0.f,0.f};

  auto stage = [&](int ee, int kt, int buf){
    const unsigned short* ap = inter + (size_t)ee * T * D;
    const unsigned short* wd = wdT + (size_t)ee * H * D;
    #pragma unroll
    for (int i = 0; i < 4; ++i){
      int task = i*256 + t, row = task >> 3, ch = task & 7, sch = ch ^ (row & 7);
      gload_lds16(ap + (size_t)(trow0 + row)*D + kt*64 + sch*8, &As[buf][task*8]);
    }
    #pragma unroll
    for (int j = 0; j < 6; ++j){
      int task = j*256 + t, row = task >> 3, ch = task & 7, sch = ch ^ (row & 7);
      gload_lds16(wd + (size_t)(ncol0 + row)*D + kt*64 + sch*8, &Bs[buf][task*8]);
    }
  };

  if (ne > 0){
    stage(g, 0, 0);

    int gkt = 0;
    for (int ei = 0; ei < ne; ++ei){
      const int ee = g + ei*4;
      const int e  = e0 + ee;
      f32x4 acc[4][6];
      #pragma unroll
      for (int i = 0; i < 4; ++i)
        #pragma unroll
        for (int j = 0; j < 6; ++j) acc[i][j] = (f32x4){0.f,0.f,0.f,0.f};

      for (int kt = 0; kt < NKT; ++kt, ++gkt){
        int cur = gkt & 1, nxt = cur ^ 1;
        int eeN, ktN;
        if (kt+1 < NKT)      { eeN = ee;     ktN = kt+1; }
        else if (ei+1 < ne)  { eeN = ee + 4; ktN = 0;    }
        else                 { eeN = ee;     ktN = kt;   }
        stage(eeN, ktN, nxt);
        asm volatile("s_waitcnt vmcnt(10)" ::: "memory");
        SCHED_FENCE(); SBAR(); SCHED_FENCE();
        #pragma unroll
        for (int kk = 0; kk < 2; ++kk){
          bf16x8 af2[4];
          #pragma unroll
          for (int mi = 0; mi < 4; ++mi){
            int row = wm*64 + mi*16 + (lane & 15);
            int pc  = (kk*4 + (lane>>4)) ^ (row & 7);
            af2[mi] = *(const bf16x8*)&As[cur][row*64 + pc*8];
          }
          bf16x8 fb[6];
          #pragma unroll
          for (int ni = 0; ni < 6; ++ni){
            int row = wn*96 + ni*16 + (lane & 15);
            int pc  = (kk*4 + (lane>>4)) ^ (row & 7);
            fb[ni] = *(const bf16x8*)&Bs[cur][row*64 + pc*8];
          }
          #pragma unroll
          for (int ni = 0; ni < 6; ++ni)
            #pragma unroll
            for (int mi = 0; mi < 4; ++mi)
              acc[mi][ni] = MFMA_BF16(af2[mi], fb[ni], acc[mi][ni]);
        }
        SBAR();
      }

      const float* bdp = bd + (size_t)e * H;
      #pragma unroll
      for (int ni = 0; ni < 6; ++ni){
        int h = ncol0 + wn*96 + ni*16 + (lane & 15);
        float bdv = bdp[h];
        #pragma unroll
        for (int mi = 0; mi < 4; ++mi){
          #pragma unroll
          for (int r = 0; r < 4; ++r){
            int trw = trow0 + wm*64 + mi*16 + (lane >> 4)*4 + r;
            float rv = rw[trw*E + e];
            oacc[mi][ni][r] += rv * (acc[mi][ni][r] + bdv);
          }
        }
      }
    }
    asm volatile("s_waitcnt vmcnt(0)" ::: "memory");
  }

  float* pp = pout + (size_t)g * T * H;
  const int accum = (e0 != 0);
  #pragma unroll
  for (int ni = 0; ni < 6; ++ni){
    int h = ncol0 + wn*96 + ni*16 + (lane & 15);
    #pragma unroll
    for (int mi = 0; mi < 4; ++mi){
      #pragma unroll
      for (int r = 0; r < 4; ++r){
        int trw = trow0 + wm*64 + mi*16 + (lane >> 4)*4 + r;
        size_t oi = (size_t)trw * H + h;
        float v = oacc[mi][ni][r];
        if (accum) v += pp[oi];
        pp[oi] = v;
      }
    }
  }
}

extern "C" void kernel_launch(void* const* d_in, const int* in_sizes, int n_in,
                              void* d_out, int out_size, void* d_ws, size_t ws_size,
                              hipStream_t stream) {
  const float* hs  = (const float*)d_in[0];
  const float* rwt = (const float*)d_in[1];
  const float* Wg  = (const float*)d_in[2];
  const float* bg  = (const float*)d_in[3];
  const float* Wu  = (const float*)d_in[4];
  const float* bu  = (const float*)d_in[5];
  const float* Wd  = (const float*)d_in[6];
  const float* bd  = (const float*)d_in[7];
  float* out = (float*)d_out;

  const size_t xbytes = (size_t)T * H * 2;          // 11.8 MB
  const size_t poutB  = (size_t)NG * T * H * 4;     // 94.4 MB
  const size_t interB = (size_t)T * D * 2;          // 11.8 MB / expert
  const size_t guB    = (size_t)NPR * H * 2;        // 35.4 MB / expert
  const size_t wdB    = (size_t)D * H * 2;          // 16.6 MB / expert
  const size_t perE   = interB + guB + 2*wdB;       // 80.4 MB / expert

  long long avail = (long long)ws_size - (long long)(xbytes + poutB);
  int EC = (int)(avail / (long long)perE);
  if (EC < 1) EC = 1;
  if (EC > 8) EC = 8;                               // >=2 chunks for overlap

  unsigned short* xb    = (unsigned short*)d_ws;
  float*          pout  = (float*)((char*)d_ws + xbytes);
  unsigned short* inter = (unsigned short*)((char*)d_ws + xbytes + poutB);
  unsigned short* wGU   = inter + (size_t)EC * T * D;
  unsigned short* wdT0  = wGU + (size_t)EC * NPR * H;
  unsigned short* wdT1  = wdT0 + (size_t)EC * D * H;

  // chunk schedule
  int e0s[16], ecs[16], nch = 0;
  for (int e0 = 0; e0 < E; e0 += EC){ e0s[nch] = e0; ecs[nch] = (E-e0 < EC)?(E-e0):EC; ++nch; }

  cvt_kernel<<<(T*H/8 + 255)/256, 256, 0, stream>>>(hs, xb, T*H/8);

  // exposed conversion: chunk 0 only
  tcvt_kernel<<<dim3(45,48,ecs[0]), 256, 0, stream>>>(Wg + (size_t)e0s[0]*H*D, wGU, 0, (size_t)NPR*H);
  tcvt_kernel<<<dim3(45,48,ecs[0]), 256, 0, stream>>>(Wu + (size_t)e0s[0]*H*D, wGU, 1, (size_t)NPR*H);
  tcvt_kernel<<<dim3(45,45,ecs[0]), 256, 0, stream>>>(Wd + (size_t)e0s[0]*H*D, wdT0, 2, (size_t)D*H);

  for (int i = 0; i < nch; ++i){
    unsigned short* wdCur = (i & 1) ? wdT1 : wdT0;
    unsigned short* wdNxt = (i & 1) ? wdT0 : wdT1;
    gateup_kernel<<<dim3(8, 24, ecs[i]), 512, 0, stream>>>(xb, wGU, bg, bu, inter, e0s[i]);
    int e0N = (i+1 < nch) ? e0s[i+1] : 0;
    int ecN = (i+1 < nch) ? ecs[i+1] : 0;
    int nstr = 3 * 45 * ecN;
    down_kernel<<<dim3(NBGEMM + nstr), 256, 0, stream>>>(
        inter, wdCur, bd, rwt, pout, e0s[i], ecs[i],
        Wg + (size_t)e0N*H*D, Wu + (size_t)e0N*H*D, Wd + (size_t)e0N*H*D,
        wGU, wdNxt, 0, ecN);
  }
  reduce_kernel<<<(T*H/4 + 255)/256, 256, 0, stream>>>(pout, out, T*H/4);
}

// Round 11
// 2133.910 us; speedup vs baseline: 2.0835x; 1.0078x over previous
//
#include <hip/hip_runtime.h>
#include <cstdint>

// GptOssExpertsLinear: E=16, H=D=2880, T=2048.
// out[t,h] = sum_e rw[t,e] * ( act(x@Wg[e]+bg, x@Wu[e]+bu) @ Wd[e] + bd )
// R11: rw folded into gateup epilogue (inter pre-scaled) -> down becomes a
// plain GEMM sum and reuses the proven R9 8-phase 256x256 template (one
// expert per grid.z, H padded to 3072, per-expert fp32 partials + reduce).
// Strips reverted (capacity-infeasible); tcvt exposed. gateup unchanged
// except the rw scaling.

#define ALPHA 1.702f
#define LIMIT 7.0f

static constexpr int E = 16;
static constexpr int H = 2880;
static constexpr int D = 2880;
static constexpr int T = 2048;
static constexpr int NKT = 45;       // K-steps of 64 (K=2880)
static constexpr int DP  = 3072;     // padded N (both GEMMs)
static constexpr int NPR = 2*DP;     // 6144 paired rows (gate|up)

typedef float        f32x4  __attribute__((ext_vector_type(4)));
typedef short        bf16x8 __attribute__((ext_vector_type(8)));

#define MFMA_BF16(a,b,c) __builtin_amdgcn_mfma_f32_16x16x32_bf16((a),(b),(c),0,0,0)
#define SBAR()        __builtin_amdgcn_s_barrier()
#define SCHED_FENCE() __builtin_amdgcn_sched_barrier(0)
#define PRIO1()       __builtin_amdgcn_s_setprio(1)
#define PRIO0()       __builtin_amdgcn_s_setprio(0)
#define LGK0()        asm volatile("s_waitcnt lgkmcnt(0)" ::: "memory")
#define VMC6()        asm volatile("s_waitcnt vmcnt(6)" ::: "memory")

__device__ __forceinline__ unsigned short f2bf(float f){
  unsigned u = __builtin_bit_cast(unsigned, f);
  u += 0x7fffu + ((u >> 16) & 1u);
  return (unsigned short)(u >> 16);
}
__device__ __forceinline__ unsigned pack2(float a, float b){
  return (unsigned)f2bf(a) | ((unsigned)f2bf(b) << 16);
}

__device__ __forceinline__ void gload_lds16(const void* g, void* l){
  __builtin_amdgcn_global_load_lds((const __attribute__((address_space(1))) unsigned*)g,
                                   (__attribute__((address_space(3))) unsigned*)l,
                                   16, 0, 0);
}

// x fp32 -> bf16, 8 elems/thread
__global__ void cvt_kernel(const float* __restrict__ in, unsigned short* __restrict__ ob, int n8){
  int i = blockIdx.x * 256 + threadIdx.x;
  if (i < n8){
    float4 a = ((const float4*)in)[2*i];
    float4 b = ((const float4*)in)[2*i+1];
    uint4 o;
    o.x = pack2(a.x, a.y); o.y = pack2(a.z, a.w);
    o.z = pack2(b.x, b.y); o.w = pack2(b.z, b.w);
    ((uint4*)ob)[i] = o;
  }
}

// W fp32 -> bf16 transpose with row remap; zero-pad rows beyond D.
// mode 0: dst row = (c/32)*64 + c%32       (gate half of paired layout)
// mode 1: dst row = (c/32)*64 + c%32 + 32  (up half)
// mode 2: dst row = c                      (plain transpose, down weights)
__global__ __launch_bounds__(256) void tcvt_kernel(
    const float* __restrict__ src, unsigned short* __restrict__ dst,
    int mode, size_t dstStride)
{
  __shared__ unsigned short tl[64*72];
  const int t = threadIdx.x;
  const float* s = src + (size_t)blockIdx.z * H * D;
  unsigned short* o = dst + (size_t)blockIdx.z * dstStride;
  const int r0 = blockIdx.x * 64, c0 = blockIdx.y * 64;

  if (c0 < D){
    int rr = t >> 2;
    #pragma unroll
    for (int p = 0; p < 4; ++p){
      int cc = ((t & 3) + p*4) * 4;
      float4 v = *(const float4*)(s + (size_t)(r0 + rr)*D + c0 + cc);
      tl[(cc+0)*72 + rr] = f2bf(v.x);
      tl[(cc+1)*72 + rr] = f2bf(v.y);
      tl[(cc+2)*72 + rr] = f2bf(v.z);
      tl[(cc+3)*72 + rr] = f2bf(v.w);
    }
    __syncthreads();
    #pragma unroll
    for (int p = 0; p < 2; ++p){
      int task = p*256 + t;
      int cl = task >> 3, ch = task & 7;
      int c = c0 + cl;
      int rowp = (mode < 2) ? ((c >> 5)*64 + (c & 31) + mode*32) : c;
      bf16x8 v = *(const bf16x8*)&tl[cl*72 + ch*8];
      *(bf16x8*)(o + (size_t)rowp*H + r0 + ch*8) = v;
    }
  } else {
    #pragma unroll
    for (int p = 0; p < 2; ++p){
      int task = p*256 + t;
      int cl = task >> 3, ch = task & 7;
      int c = c0 + cl;
      int rowp = (mode < 2) ? ((c >> 5)*64 + (c & 31) + mode*32) : c;
      bf16x8 z = (bf16x8){0,0,0,0,0,0,0,0};
      *(bf16x8*)(o + (size_t)rowp*H + r0 + ch*8) = z;
    }
  }
}

// sum nz per-expert partials -> out
__global__ void reduce_kernel(const float* __restrict__ p, float* __restrict__ out,
                              int n4, int nz){
  int i = blockIdx.x * 256 + threadIdx.x;
  if (i < n4){
    f32x4 a = ((const f32x4*)p)[i];
    for (int g = 1; g < nz; ++g)
      a += ((const f32x4*)(p + (size_t)g * T * H))[i];
    ((f32x4*)out)[i] = a;
  }
}

// ---------------- gate+up fused GEMM + activation (R9 + rw scaling) --------
// grid (8, 24, ec); 512 thr = 8 waves (2M x 4N); wave tile 128x64 paired.
__global__ __launch_bounds__(512, 2) void gateup_kernel(
    const unsigned short* __restrict__ xb,    // [T][H] bf16
    const unsigned short* __restrict__ wGU,   // [ec][6144][H] paired bf16
    const float* __restrict__ bg,
    const float* __restrict__ bu,
    const float* __restrict__ rw,             // [T][E]
    unsigned short* __restrict__ inter,       // [ec][T][D] bf16 (rw-scaled)
    int e0)
{
  __shared__ short As[2][256*64];   // 64KB (quarter-interleaved rows)
  __shared__ short Bs[2][256*64];   // 64KB => 128KB total

  const int t = threadIdx.x, lane = t & 63, wv = t >> 6;
  const int wm = wv >> 2, wn = wv & 3;

  int nbx = gridDim.x, nby = gridDim.y;
  int lin = blockIdx.x + nbx*(blockIdx.y + nby*blockIdx.z);
  int per = (nbx*nby*gridDim.z) >> 3;
  int id2 = (lin & 7)*per + (lin >> 3);
  int bx = id2 % nbx; int rem = id2 / nbx;
  int by = rem % nby; int ez = rem / nby;

  const int trow0 = bx*256, ncol0 = by*256;
  const int e = e0 + ez;
  const unsigned short* wg = wGU + (size_t)ez * NPR * H;

  f32x4 acc[8][4];
  #pragma unroll
  for (int i = 0; i < 8; ++i)
    #pragma unroll
    for (int j = 0; j < 4; ++j) acc[i][j] = (f32x4){0.f,0.f,0.f,0.f};

  auto stageA = [&](int kt, int b, int h){
    #pragma unroll
    for (int r2 = 0; r2 < 2; ++r2){
      int task = r2*512 + t;
      int ps = task >> 3, ch = task & 7, sch = ch ^ (ps & 7);
      int lr = h*64 + (ps & 63) + ((ps >> 6) << 7);
      gload_lds16(xb + (size_t)(trow0 + lr)*H + kt*64 + sch*8,
                  &As[b][h*8192 + task*8]);
    }
  };
  auto stageB = [&](int kt, int b, int h){
    #pragma unroll
    for (int r2 = 0; r2 < 2; ++r2){
      int task = r2*512 + t;
      int ps = task >> 3, ch = task & 7, sch = ch ^ (ps & 7);
      int lr = h*32 + ((ps >> 5) << 6) + (ps & 31);
      gload_lds16(wg + (size_t)(ncol0 + lr)*H + kt*64 + sch*8,
                  &Bs[b][h*8192 + task*8]);
    }
  };

  bf16x8 af[4][2], bLo[2][2], bHi[2][2];
  auto readAh = [&](int b, int qa){
    #pragma unroll
    for (int mi = 0; mi < 4; ++mi){
      int r = wm*128 + qa*64 + mi*16 + (lane & 15);
      int q = r >> 6, qs = ((q & 1) << 1) | (q >> 1);
      int pr = qs*64 + (r & 63);
      #pragma unroll
      for (int kk = 0; kk < 2; ++kk){
        int pc = (kk*4 + (lane >> 4)) ^ (pr & 7);
        af[mi][kk] = *(const bf16x8*)&As[b][pr*64 + pc*8];
      }
    }
  };
  auto readBh = [&](bf16x8 (&bf)[2][2], int b, int hb){
    #pragma unroll
    for (int ni = 0; ni < 2; ++ni){
      int rB = wn*64 + hb*32 + ni*16 + (lane & 15);
      int pr = ((rB >> 5) & 1)*128 + (rB >> 6)*32 + (rB & 31);
      #pragma unroll
      for (int kk = 0; kk < 2; ++kk){
        int pc = (kk*4 + (lane >> 4)) ^ (pr & 7);
        bf[ni][kk] = *(const bf16x8*)&Bs[b][pr*64 + pc*8];
      }
    }
  };
  auto mfmaQ = [&](bf16x8 (&bf)[2][2], int qa, int hb){
    #pragma unroll
    for (int kk = 0; kk < 2; ++kk)
      #pragma unroll
      for (int ni = 0; ni < 2; ++ni)
        #pragma unroll
        for (int mi = 0; mi < 4; ++mi)
          acc[qa*4+mi][hb*2+ni] = MFMA_BF16(af[mi][kk], bf[ni][kk], acc[qa*4+mi][hb*2+ni]);
  };

  stageA(0,0,0); stageB(0,0,0); stageB(0,0,1); stageA(0,0,1);
  stageA(1,1,0); stageB(1,1,0); stageB(1,1,1);
  asm volatile("s_waitcnt vmcnt(8)" ::: "memory");
  SBAR();

  for (int it = 0; it < 22; ++it){
    int kt = 2*it;
    int ktA = (kt+2 < NKT) ? kt+2 : NKT-1;
    int ktB = (kt+3 < NKT) ? kt+3 : NKT-1;
    readAh(0, 0); readBh(bLo, 0, 0);
    stageA(kt+1, 1, 1);
    SCHED_FENCE(); SBAR(); LGK0(); SCHED_FENCE();
    PRIO1(); mfmaQ(bLo, 0, 0); PRIO0();
    VMC6(); SBAR();
    readBh(bHi, 0, 1);
    stageA(ktA, 0, 0);
    SCHED_FENCE(); SBAR(); LGK0(); SCHED_FENCE();
    PRIO1(); mfmaQ(bHi, 0, 1); PRIO0();
    VMC6(); SBAR();
    readAh(0, 1);
    stageB(ktA, 0, 0);
    SCHED_FENCE(); SBAR(); LGK0(); SCHED_FENCE();
    PRIO1(); mfmaQ(bHi, 1, 1); PRIO0();
    VMC6(); SBAR();
    stageB(ktA, 0, 1);
    SCHED_FENCE(); SBAR(); SCHED_FENCE();
    PRIO1(); mfmaQ(bLo, 1, 0); PRIO0();
    VMC6(); SBAR();
    readAh(1, 0); readBh(bLo, 1, 0);
    stageA(ktA, 0, 1);
    SCHED_FENCE(); SBAR(); LGK0(); SCHED_FENCE();
    PRIO1(); mfmaQ(bLo, 0, 0); PRIO0();
    VMC6(); SBAR();
    readBh(bHi, 1, 1);
    stageA(ktB, 1, 0);
    SCHED_FENCE(); SBAR(); LGK0(); SCHED_FENCE();
    PRIO1(); mfmaQ(bHi, 0, 1); PRIO0();
    VMC6(); SBAR();
    readAh(1, 1);
    stageB(ktB, 1, 0);
    SCHED_FENCE(); SBAR(); LGK0(); SCHED_FENCE();
    PRIO1(); mfmaQ(bHi, 1, 1); PRIO0();
    VMC6(); SBAR();
    stageB(ktB, 1, 1);
    SCHED_FENCE(); SBAR(); SCHED_FENCE();
    PRIO1(); mfmaQ(bLo, 1, 0); PRIO0();
    VMC6(); SBAR();
  }

  asm volatile("s_waitcnt vmcnt(0)" ::: "memory");
  SBAR();
  readAh(0, 0); readBh(bLo, 0, 0); readBh(bHi, 0, 1);
  LGK0(); SCHED_FENCE();
  mfmaQ(bLo, 0, 0); mfmaQ(bHi, 0, 1);
  readAh(0, 1);
  LGK0(); SCHED_FENCE();
  mfmaQ(bHi, 1, 1); mfmaQ(bLo, 1, 0);

  // epilogue: bias + clamp + glu, scaled by rw -> inter bf16
  const float* bgp = bg + (size_t)e * D;
  const float* bup = bu + (size_t)e * D;
  unsigned short* ip = inter + (size_t)ez * T * D;
  const int dbase = (by*4 + wn) * 32;
  #pragma unroll
  for (int g = 0; g < 2; ++g){
    int d0 = dbase + g*16;
    if (d0 < D){
      int d = d0 + (lane & 15);
      float bgv = bgp[d], buv = bup[d];
      #pragma unroll
      for (int mi = 0; mi < 8; ++mi){
        #pragma unroll
        for (int r = 0; r < 4; ++r){
          int trw = trow0 + wm*128 + mi*16 + (lane >> 4)*4 + r;
          float gv = acc[mi][g][r] + bgv;
          float uv = acc[mi][g+2][r] + buv;
          gv = fminf(gv, LIMIT);
          uv = fminf(fmaxf(uv, -LIMIT), LIMIT);
          float glu = gv / (1.f + __expf(-ALPHA * gv));
          float rv = rw[trw*E + e];
          ip[(size_t)trw * D + d] = f2bf(rv * (uv + 1.f) * glu);
        }
      }
    }
  }
}

// ---------------- down GEMM (8-phase 256x256, one expert per z) ------------
// grid (8, 12, ec); 512 thr = 8 waves; wave tile 128x64.
// A = rw-scaled inter (expert ez); B = padded Wd^T; writes pout[ez] fp32.
__global__ __launch_bounds__(512, 2) void down_kernel(
    const unsigned short* __restrict__ inter, // [ec][T][D] bf16 (rw-scaled)
    const unsigned short* __restrict__ wdT,   // [ec][3072][D] bf16 padded
    const float* __restrict__ bd,
    const float* __restrict__ rw,             // [T][E]
    float* __restrict__ pout,                 // [EC][T][H] fp32 partials
    int e0)
{
  __shared__ short As[2][256*64];
  __shared__ short Bs[2][256*64];

  const int t = threadIdx.x, lane = t & 63, wv = t >> 6;
  const int wm = wv >> 2, wn = wv & 3;

  int nbx = gridDim.x, nby = gridDim.y;
  int lin = blockIdx.x + nbx*(blockIdx.y + nby*blockIdx.z);
  int per = (nbx*nby*gridDim.z) >> 3;
  int id2 = (lin & 7)*per + (lin >> 3);
  int bx = id2 % nbx; int rem = id2 / nbx;
  int by = rem % nby; int ez = rem / nby;

  const int trow0 = bx*256, ncol0 = by*256;
  const int e = e0 + ez;
  const unsigned short* ap = inter + (size_t)ez * T * D;
  const unsigned short* wd = wdT + (size_t)ez * DP * D;

  f32x4 acc[8][4];
  #pragma unroll
  for (int i = 0; i < 8; ++i)
    #pragma unroll
    for (int j = 0; j < 4; ++j) acc[i][j] = (f32x4){0.f,0.f,0.f,0.f};

  auto stageA = [&](int kt, int b, int h){
    #pragma unroll
    for (int r2 = 0; r2 < 2; ++r2){
      int task = r2*512 + t;
      int ps = task >> 3, ch = task & 7, sch = ch ^ (ps & 7);
      int lr = h*64 + (ps & 63) + ((ps >> 6) << 7);
      gload_lds16(ap + (size_t)(trow0 + lr)*D + kt*64 + sch*8,
                  &As[b][h*8192 + task*8]);
    }
  };
  auto stageB = [&](int kt, int b, int h){
    #pragma unroll
    for (int r2 = 0; r2 < 2; ++r2){
      int task = r2*512 + t;
      int ps = task >> 3, ch = task & 7, sch = ch ^ (ps & 7);
      int lr = h*32 + ((ps >> 5) << 6) + (ps & 31);
      gload_lds16(wd + (size_t)(ncol0 + lr)*D + kt*64 + sch*8,
                  &Bs[b][h*8192 + task*8]);
    }
  };

  bf16x8 af[4][2], bLo[2][2], bHi[2][2];
  auto readAh = [&](int b, int qa){
    #pragma unroll
    for (int mi = 0; mi < 4; ++mi){
      int r = wm*128 + qa*64 + mi*16 + (lane & 15);
      int q = r >> 6, qs = ((q & 1) << 1) | (q >> 1);
      int pr = qs*64 + (r & 63);
      #pragma unroll
      for (int kk = 0; kk < 2; ++kk){
        int pc = (kk*4 + (lane >> 4)) ^ (pr & 7);
        af[mi][kk] = *(const bf16x8*)&As[b][pr*64 + pc*8];
      }
    }
  };
  auto readBh = [&](bf16x8 (&bf)[2][2], int b, int hb){
    #pragma unroll
    for (int ni = 0; ni < 2; ++ni){
      int rB = wn*64 + hb*32 + ni*16 + (lane & 15);
      int pr = ((rB >> 5) & 1)*128 + (rB >> 6)*32 + (rB & 31);
      #pragma unroll
      for (int kk = 0; kk < 2; ++kk){
        int pc = (kk*4 + (lane >> 4)) ^ (pr & 7);
        bf[ni][kk] = *(const bf16x8*)&Bs[b][pr*64 + pc*8];
      }
    }
  };
  auto mfmaQ = [&](bf16x8 (&bf)[2][2], int qa, int hb){
    #pragma unroll
    for (int kk = 0; kk < 2; ++kk)
      #pragma unroll
      for (int ni = 0; ni < 2; ++ni)
        #pragma unroll
        for (int mi = 0; mi < 4; ++mi)
          acc[qa*4+mi][hb*2+ni] = MFMA_BF16(af[mi][kk], bf[ni][kk], acc[qa*4+mi][hb*2+ni]);
  };

  stageA(0,0,0); stageB(0,0,0); stageB(0,0,1); stageA(0,0,1);
  stageA(1,1,0); stageB(1,1,0); stageB(1,1,1);
  asm volatile("s_waitcnt vmcnt(8)" ::: "memory");
  SBAR();

  for (int it = 0; it < 22; ++it){
    int kt = 2*it;
    int ktA = (kt+2 < NKT) ? kt+2 : NKT-1;
    int ktB = (kt+3 < NKT) ? kt+3 : NKT-1;
    readAh(0, 0); readBh(bLo, 0, 0);
    stageA(kt+1, 1, 1);
    SCHED_FENCE(); SBAR(); LGK0(); SCHED_FENCE();
    PRIO1(); mfmaQ(bLo, 0, 0); PRIO0();
    VMC6(); SBAR();
    readBh(bHi, 0, 1);
    stageA(ktA, 0, 0);
    SCHED_FENCE(); SBAR(); LGK0(); SCHED_FENCE();
    PRIO1(); mfmaQ(bHi, 0, 1); PRIO0();
    VMC6(); SBAR();
    readAh(0, 1);
    stageB(ktA, 0, 0);
    SCHED_FENCE(); SBAR(); LGK0(); SCHED_FENCE();
    PRIO1(); mfmaQ(bHi, 1, 1); PRIO0();
    VMC6(); SBAR();
    stageB(ktA, 0, 1);
    SCHED_FENCE(); SBAR(); SCHED_FENCE();
    PRIO1(); mfmaQ(bLo, 1, 0); PRIO0();
    VMC6(); SBAR();
    readAh(1, 0); readBh(bLo, 1, 0);
    stageA(ktA, 0, 1);
    SCHED_FENCE(); SBAR(); LGK0(); SCHED_FENCE();
    PRIO1(); mfmaQ(bLo, 0, 0); PRIO0();
    VMC6(); SBAR();
    readBh(bHi, 1, 1);
    stageA(ktB, 1, 0);
    SCHED_FENCE(); SBAR(); LGK0(); SCHED_FENCE();
    PRIO1(); mfmaQ(bHi, 0, 1); PRIO0();
    VMC6(); SBAR();
    readAh(1, 1);
    stageB(ktB, 1, 0);
    SCHED_FENCE(); SBAR(); LGK0(); SCHED_FENCE();
    PRIO1(); mfmaQ(bHi, 1, 1); PRIO0();
    VMC6(); SBAR();
    stageB(ktB, 1, 1);
    SCHED_FENCE(); SBAR(); SCHED_FENCE();
    PRIO1(); mfmaQ(bLo, 1, 0); PRIO0();
    VMC6(); SBAR();
  }

  asm volatile("s_waitcnt vmcnt(0)" ::: "memory");
  SBAR();
  readAh(0, 0); readBh(bLo, 0, 0); readBh(bHi, 0, 1);
  LGK0(); SCHED_FENCE();
  mfmaQ(bLo, 0, 0); mfmaQ(bHi, 0, 1);
  readAh(0, 1);
  LGK0(); SCHED_FENCE();
  mfmaQ(bHi, 1, 1); mfmaQ(bLo, 1, 0);

  // epilogue: partial[ez] = acc + rw*bd (accumulate across chunks)
  const float* bdp = bd + (size_t)e * H;
  float* pp = pout + (size_t)ez * T * H;
  const int accum = (e0 != 0);
  #pragma unroll
  for (int j = 0; j < 4; ++j){
    int h0 = ncol0 + wn*64 + j*16;
    if (h0 < H){
      int h = h0 + (lane & 15);
      float bdv = bdp[h];
      #pragma unroll
      for (int mi = 0; mi < 8; ++mi){
        #pragma unroll
        for (int r = 0; r < 4; ++r){
          int trw = trow0 + wm*128 + mi*16 + (lane >> 4)*4 + r;
          float rv = rw[trw*E + e];
          size_t oi = (size_t)trw * H + h;
          float v = acc[mi][j][r] + rv * bdv;
          if (accum) v += pp[oi];
          pp[oi] = v;
        }
      }
    }
  }
}

extern "C" void kernel_launch(void* const* d_in, const int* in_sizes, int n_in,
                              void* d_out, int out_size, void* d_ws, size_t ws_size,
                              hipStream_t stream) {
  const float* hs  = (const float*)d_in[0];
  const float* rwt = (const float*)d_in[1];
  const float* Wg  = (const float*)d_in[2];
  const float* bg  = (const float*)d_in[3];
  const float* Wu  = (const float*)d_in[4];
  const float* bu  = (const float*)d_in[5];
  const float* Wd  = (const float*)d_in[6];
  const float* bd  = (const float*)d_in[7];
  float* out = (float*)d_out;

  const size_t xbytes = (size_t)T * H * 2;          // 11.8 MB
  const size_t interB = (size_t)T * D * 2;          // 11.8 MB / expert
  const size_t guB    = (size_t)NPR * H * 2;        // 35.4 MB / expert
  const size_t wdB    = (size_t)DP * D * 2;         // 17.7 MB / expert (padded)
  const size_t poutE  = (size_t)T * H * 4;          // 23.6 MB / expert slot
  const size_t perE   = interB + guB + wdB + poutE; // 88.5 MB / expert

  long long avail = (long long)ws_size - (long long)xbytes;
  int EC = (int)(avail / (long long)perE);
  if (EC < 1) EC = 1;
  if (EC > E) EC = E;

  unsigned short* xb    = (unsigned short*)d_ws;
  float*          pout  = (float*)((char*)d_ws + xbytes);
  unsigned short* inter = (unsigned short*)((char*)d_ws + xbytes + (size_t)EC*poutE);
  unsigned short* wGU   = inter + (size_t)EC * T * D;
  unsigned short* wdT   = wGU + (size_t)EC * NPR * H;

  cvt_kernel<<<(T*H/8 + 255)/256, 256, 0, stream>>>(hs, xb, T*H/8);

  for (int e0 = 0; e0 < E; e0 += EC){
    int ec = (E - e0 < EC) ? (E - e0) : EC;
    tcvt_kernel<<<dim3(45,48,ec), 256, 0, stream>>>(Wg + (size_t)e0*H*D, wGU, 0, (size_t)NPR*H);
    tcvt_kernel<<<dim3(45,48,ec), 256, 0, stream>>>(Wu + (size_t)e0*H*D, wGU, 1, (size_t)NPR*H);
    gateup_kernel<<<dim3(8, 24, ec), 512, 0, stream>>>(xb, wGU, bg, bu, rwt, inter, e0);
    tcvt_kernel<<<dim3(45,48,ec), 256, 0, stream>>>(Wd + (size_t)e0*H*D, wdT, 2, (size_t)DP*D);
    down_kernel<<<dim3(8, 12, ec), 512, 0, stream>>>(inter, wdT, bd, rwt, pout, e0);
  }
  reduce_kernel<<<(T*H/4 + 255)/256, 256, 0, stream>>>(pout, out, T*H/4, EC);
}

// Round 13
// 2112.323 us; speedup vs baseline: 2.1048x; 1.0102x over previous
//
#include <hip/hip_runtime.h>
#include <cstdint>

// GptOssExpertsLinear: E=16, H=D=2880, T=2048.
// out[t,h] = sum_e rw[t,e] * ( act(x@Wg[e]+bg, x@Wu[e]+bu) @ Wd[e] + bd )
// R13 = R12 + tail-parity fix: the 8-phase template completes tile kt+1's
// A-hi in the NEXT iteration's p1, so an EVEN trip count leaves the last
// tile's A-hi unstaged (R12 bug, absmax 1.82). Fix: stage it post-loop
// before the vmcnt(0)+barrier tail.
// Structure: rw folded into gateup -> down is ONE GEMM over concatenated
// K = EC*2880, split-K=4, 8-phase 256x256 template. Bias via rank-16 rw@bd
// in reduce. Gateup pairing pad 2944.

#define ALPHA 1.702f
#define LIMIT 7.0f

static constexpr int E = 16;
static constexpr int H = 2880;
static constexpr int D = 2880;
static constexpr int T = 2048;
static constexpr int NKT = 45;       // gateup K-steps of 64 (K=2880)
static constexpr int NPR = 5888;     // paired gate|up rows (2*2944)
static constexpr int HP  = 3072;     // padded H for down N
static constexpr int NZ  = 4;        // down split-K partials

typedef float        f32x4  __attribute__((ext_vector_type(4)));
typedef short        bf16x8 __attribute__((ext_vector_type(8)));

#define MFMA_BF16(a,b,c) __builtin_amdgcn_mfma_f32_16x16x32_bf16((a),(b),(c),0,0,0)
#define SBAR()        __builtin_amdgcn_s_barrier()
#define SCHED_FENCE() __builtin_amdgcn_sched_barrier(0)
#define PRIO1()       __builtin_amdgcn_s_setprio(1)
#define PRIO0()       __builtin_amdgcn_s_setprio(0)
#define LGK0()        asm volatile("s_waitcnt lgkmcnt(0)" ::: "memory")
#define VMC6()        asm volatile("s_waitcnt vmcnt(6)" ::: "memory")

__device__ __forceinline__ unsigned short f2bf(float f){
  unsigned u = __builtin_bit_cast(unsigned, f);
  u += 0x7fffu + ((u >> 16) & 1u);
  return (unsigned short)(u >> 16);
}
__device__ __forceinline__ unsigned pack2(float a, float b){
  return (unsigned)f2bf(a) | ((unsigned)f2bf(b) << 16);
}

__device__ __forceinline__ void gload_lds16(const void* g, void* l){
  __builtin_amdgcn_global_load_lds((const __attribute__((address_space(1))) unsigned*)g,
                                   (__attribute__((address_space(3))) unsigned*)l,
                                   16, 0, 0);
}

// x fp32 -> bf16, 8 elems/thread
__global__ void cvt_kernel(const float* __restrict__ in, unsigned short* __restrict__ ob, int n8){
  int i = blockIdx.x * 256 + threadIdx.x;
  if (i < n8){
    float4 a = ((const float4*)in)[2*i];
    float4 b = ((const float4*)in)[2*i+1];
    uint4 o;
    o.x = pack2(a.x, a.y); o.y = pack2(a.z, a.w);
    o.z = pack2(b.x, b.y); o.w = pack2(b.z, b.w);
    ((uint4*)ob)[i] = o;
  }
}

// W fp32 -> bf16 transpose with row remap; zero-pad rows beyond D.
// mode 0: dst row = (c/32)*64 + c%32       (gate half of paired layout)
// mode 1: dst row = (c/32)*64 + c%32 + 32  (up half)
// mode 2: dst row = c                      (plain transpose, down weights)
// dst element = dst + z*expStride + rowp*rowStride + k
__global__ __launch_bounds__(256) void tcvt_kernel(
    const float* __restrict__ src, unsigned short* __restrict__ dst,
    int mode, size_t expStride, size_t rowStride)
{
  __shared__ unsigned short tl[64*72];
  const int t = threadIdx.x;
  const float* s = src + (size_t)blockIdx.z * H * D;
  unsigned short* o = dst + (size_t)blockIdx.z * expStride;
  const int r0 = blockIdx.x * 64, c0 = blockIdx.y * 64;

  if (c0 < D){
    int rr = t >> 2;
    #pragma unroll
    for (int p = 0; p < 4; ++p){
      int cc = ((t & 3) + p*4) * 4;
      float4 v = *(const float4*)(s + (size_t)(r0 + rr)*D + c0 + cc);
      tl[(cc+0)*72 + rr] = f2bf(v.x);
      tl[(cc+1)*72 + rr] = f2bf(v.y);
      tl[(cc+2)*72 + rr] = f2bf(v.z);
      tl[(cc+3)*72 + rr] = f2bf(v.w);
    }
    __syncthreads();
    #pragma unroll
    for (int p = 0; p < 2; ++p){
      int task = p*256 + t;
      int cl = task >> 3, ch = task & 7;
      int c = c0 + cl;
      int rowp = (mode < 2) ? ((c >> 5)*64 + (c & 31) + mode*32) : c;
      bf16x8 v = *(const bf16x8*)&tl[cl*72 + ch*8];
      *(bf16x8*)(o + (size_t)rowp*rowStride + r0 + ch*8) = v;
    }
  } else {
    #pragma unroll
    for (int p = 0; p < 2; ++p){
      int task = p*256 + t;
      int cl = task >> 3, ch = task & 7;
      int c = c0 + cl;
      int rowp = (mode < 2) ? ((c >> 5)*64 + (c & 31) + mode*32) : c;
      bf16x8 z = (bf16x8){0,0,0,0,0,0,0,0};
      *(bf16x8*)(o + (size_t)rowp*rowStride + r0 + ch*8) = z;
    }
  }
}

// sum NZ split-K partials + rank-E bias term rw@bd -> out
__global__ void reduce_kernel(const float* __restrict__ p,
                              const float* __restrict__ rw,
                              const float* __restrict__ bd,
                              float* __restrict__ out, int n4){
  int i = blockIdx.x * 256 + threadIdx.x;
  if (i < n4){
    int t  = i / (H/4);
    int h4 = (i % (H/4)) * 4;
    f32x4 a = ((const f32x4*)p)[i];
    #pragma unroll
    for (int z = 1; z < NZ; ++z)
      a += ((const f32x4*)(p + (size_t)z * T * H))[i];
    #pragma unroll
    for (int e = 0; e < E; ++e){
      float r = rw[t*E + e];
      f32x4 b = *(const f32x4*)(bd + (size_t)e*H + h4);
      a += r * b;
    }
    ((f32x4*)out)[i] = a;
  }
}

// ---------------- gate+up fused GEMM + activation (8-phase 256x256) --------
// grid (8, 23, ec); 512 thr = 8 waves (2M x 4N); wave tile 128x64 paired.
__global__ __launch_bounds__(512, 2) void gateup_kernel(
    const unsigned short* __restrict__ xb,    // [T][H] bf16
    const unsigned short* __restrict__ wGU,   // [ec][5888][H] paired bf16
    const float* __restrict__ bg,
    const float* __restrict__ bu,
    const float* __restrict__ rw,             // [T][E]
    unsigned short* __restrict__ inter,       // [T][KD] bf16 (rw-scaled)
    int e0, int KD)
{
  __shared__ short As[2][256*64];   // 64KB (quarter-interleaved rows)
  __shared__ short Bs[2][256*64];   // 64KB => 128KB total

  const int t = threadIdx.x, lane = t & 63, wv = t >> 6;
  const int wm = wv >> 2, wn = wv & 3;

  int nbx = gridDim.x, nby = gridDim.y;
  int lin = blockIdx.x + nbx*(blockIdx.y + nby*blockIdx.z);
  int per = (nbx*nby*gridDim.z) >> 3;
  int id2 = (lin & 7)*per + (lin >> 3);
  int bx = id2 % nbx; int rem = id2 / nbx;
  int by = rem % nby; int ez = rem / nby;

  const int trow0 = bx*256, ncol0 = by*256;
  const int e = e0 + ez;
  const unsigned short* wg = wGU + (size_t)ez * NPR * H;

  f32x4 acc[8][4];
  #pragma unroll
  for (int i = 0; i < 8; ++i)
    #pragma unroll
    for (int j = 0; j < 4; ++j) acc[i][j] = (f32x4){0.f,0.f,0.f,0.f};

  auto stageA = [&](int kt, int b, int h){
    #pragma unroll
    for (int r2 = 0; r2 < 2; ++r2){
      int task = r2*512 + t;
      int ps = task >> 3, ch = task & 7, sch = ch ^ (ps & 7);
      int lr = h*64 + (ps & 63) + ((ps >> 6) << 7);
      gload_lds16(xb + (size_t)(trow0 + lr)*H + kt*64 + sch*8,
                  &As[b][h*8192 + task*8]);
    }
  };
  auto stageB = [&](int kt, int b, int h){
    #pragma unroll
    for (int r2 = 0; r2 < 2; ++r2){
      int task = r2*512 + t;
      int ps = task >> 3, ch = task & 7, sch = ch ^ (ps & 7);
      int lr = h*32 + ((ps >> 5) << 6) + (ps & 31);
      gload_lds16(wg + (size_t)(ncol0 + lr)*H + kt*64 + sch*8,
                  &Bs[b][h*8192 + task*8]);
    }
  };

  bf16x8 af[4][2], bLo[2][2], bHi[2][2];
  auto readAh = [&](int b, int qa){
    #pragma unroll
    for (int mi = 0; mi < 4; ++mi){
      int r = wm*128 + qa*64 + mi*16 + (lane & 15);
      int q = r >> 6, qs = ((q & 1) << 1) | (q >> 1);
      int pr = qs*64 + (r & 63);
      #pragma unroll
      for (int kk = 0; kk < 2; ++kk){
        int pc = (kk*4 + (lane >> 4)) ^ (pr & 7);
        af[mi][kk] = *(const bf16x8*)&As[b][pr*64 + pc*8];
      }
    }
  };
  auto readBh = [&](bf16x8 (&bf)[2][2], int b, int hb){
    #pragma unroll
    for (int ni = 0; ni < 2; ++ni){
      int rB = wn*64 + hb*32 + ni*16 + (lane & 15);
      int pr = ((rB >> 5) & 1)*128 + (rB >> 6)*32 + (rB & 31);
      #pragma unroll
      for (int kk = 0; kk < 2; ++kk){
        int pc = (kk*4 + (lane >> 4)) ^ (pr & 7);
        bf[ni][kk] = *(const bf16x8*)&Bs[b][pr*64 + pc*8];
      }
    }
  };
  auto mfmaQ = [&](bf16x8 (&bf)[2][2], int qa, int hb){
    #pragma unroll
    for (int kk = 0; kk < 2; ++kk)
      #pragma unroll
      for (int ni = 0; ni < 2; ++ni)
        #pragma unroll
        for (int mi = 0; mi < 4; ++mi)
          acc[qa*4+mi][hb*2+ni] = MFMA_BF16(af[mi][kk], bf[ni][kk], acc[qa*4+mi][hb*2+ni]);
  };

  stageA(0,0,0); stageB(0,0,0); stageB(0,0,1); stageA(0,0,1);
  stageA(1,1,0); stageB(1,1,0); stageB(1,1,1);
  asm volatile("s_waitcnt vmcnt(8)" ::: "memory");
  SBAR();

  for (int it = 0; it < 22; ++it){
    int kt = 2*it;
    int ktA = (kt+2 < NKT) ? kt+2 : NKT-1;
    int ktB = (kt+3 < NKT) ? kt+3 : NKT-1;
    readAh(0, 0); readBh(bLo, 0, 0);
    stageA(kt+1, 1, 1);
    SCHED_FENCE(); SBAR(); LGK0(); SCHED_FENCE();
    PRIO1(); mfmaQ(bLo, 0, 0); PRIO0();
    VMC6(); SBAR();
    readBh(bHi, 0, 1);
    stageA(ktA, 0, 0);
    SCHED_FENCE(); SBAR(); LGK0(); SCHED_FENCE();
    PRIO1(); mfmaQ(bHi, 0, 1); PRIO0();
    VMC6(); SBAR();
    readAh(0, 1);
    stageB(ktA, 0, 0);
    SCHED_FENCE(); SBAR(); LGK0(); SCHED_FENCE();
    PRIO1(); mfmaQ(bHi, 1, 1); PRIO0();
    VMC6(); SBAR();
    stageB(ktA, 0, 1);
    SCHED_FENCE(); SBAR(); SCHED_FENCE();
    PRIO1(); mfmaQ(bLo, 1, 0); PRIO0();
    VMC6(); SBAR();
    readAh(1, 0); readBh(bLo, 1, 0);
    stageA(ktA, 0, 1);
    SCHED_FENCE(); SBAR(); LGK0(); SCHED_FENCE();
    PRIO1(); mfmaQ(bLo, 0, 0); PRIO0();
    VMC6(); SBAR();
    readBh(bHi, 1, 1);
    stageA(ktB, 1, 0);
    SCHED_FENCE(); SBAR(); LGK0(); SCHED_FENCE();
    PRIO1(); mfmaQ(bHi, 0, 1); PRIO0();
    VMC6(); SBAR();
    readAh(1, 1);
    stageB(ktB, 1, 0);
    SCHED_FENCE(); SBAR(); LGK0(); SCHED_FENCE();
    PRIO1(); mfmaQ(bHi, 1, 1); PRIO0();
    VMC6(); SBAR();
    stageB(ktB, 1, 1);
    SCHED_FENCE(); SBAR(); SCHED_FENCE();
    PRIO1(); mfmaQ(bLo, 1, 0); PRIO0();
    VMC6(); SBAR();
  }

  asm volatile("s_waitcnt vmcnt(0)" ::: "memory");
  SBAR();
  readAh(0, 0); readBh(bLo, 0, 0); readBh(bHi, 0, 1);
  LGK0(); SCHED_FENCE();
  mfmaQ(bLo, 0, 0); mfmaQ(bHi, 0, 1);
  readAh(0, 1);
  LGK0(); SCHED_FENCE();
  mfmaQ(bHi, 1, 1); mfmaQ(bLo, 1, 0);

  // epilogue: bias + clamp + glu, scaled by rw -> inter[t][ez*D + d]
  const float* bgp = bg + (size_t)e * D;
  const float* bup = bu + (size_t)e * D;
  unsigned short* ip = inter + (size_t)ez * D;
  const int dbase = (by*4 + wn) * 32;
  #pragma unroll
  for (int g = 0; g < 2; ++g){
    int d0 = dbase + g*16;
    if (d0 < D){
      int d = d0 + (lane & 15);
      float bgv = bgp[d], buv = bup[d];
      #pragma unroll
      for (int mi = 0; mi < 8; ++mi){
        #pragma unroll
        for (int r = 0; r < 4; ++r){
          int trw = trow0 + wm*128 + mi*16 + (lane >> 4)*4 + r;
          float gv = acc[mi][g][r] + bgv;
          float uv = acc[mi][g+2][r] + buv;
          gv = fminf(gv, LIMIT);
          uv = fminf(fmaxf(uv, -LIMIT), LIMIT);
          float glu = gv / (1.f + __expf(-ALPHA * gv));
          float rv = rw[trw*E + e];
          ip[(size_t)trw * KD + d] = f2bf(rv * (uv + 1.f) * glu);
        }
      }
    }
  }
}

// ---------------- down: single GEMM over concatenated K, split-K=4 ---------
// grid (8, 12, NZ); 512 thr = 8 waves; tile 256x256; generic trip count.
__global__ __launch_bounds__(512, 2) void down_kernel(
    const unsigned short* __restrict__ inter, // [T][KD] bf16 (rw-scaled)
    const unsigned short* __restrict__ wdA,   // [3072][KD] bf16 (pad rows 0)
    float* __restrict__ pout,                 // [NZ][T][H] fp32 partials
    int nk64, int KD, int accum)
{
  __shared__ short As[2][256*64];
  __shared__ short Bs[2][256*64];

  const int t = threadIdx.x, lane = t & 63, wv = t >> 6;
  const int wm = wv >> 2, wn = wv & 3;

  int nbx = gridDim.x, nby = gridDim.y;
  int lin = blockIdx.x + nbx*(blockIdx.y + nby*blockIdx.z);
  int per = (nbx*nby*gridDim.z) >> 3;
  int id2 = (lin & 7)*per + (lin >> 3);
  int bx = id2 % nbx; int rem = id2 / nbx;
  int by = rem % nby; int z  = rem / nby;

  const int trow0 = bx*256, ncol0 = by*256;
  const int ksteps = nk64 >> 2;           // per split-K slice
  const int kst = z * ksteps, kend = kst + ksteps;

  f32x4 acc[8][4];
  #pragma unroll
  for (int i = 0; i < 8; ++i)
    #pragma unroll
    for (int j = 0; j < 4; ++j) acc[i][j] = (f32x4){0.f,0.f,0.f,0.f};

  auto stageA = [&](int kt, int b, int h){
    #pragma unroll
    for (int r2 = 0; r2 < 2; ++r2){
      int task = r2*512 + t;
      int ps = task >> 3, ch = task & 7, sch = ch ^ (ps & 7);
      int lr = h*64 + (ps & 63) + ((ps >> 6) << 7);
      gload_lds16(inter + (size_t)(trow0 + lr)*KD + kt*64 + sch*8,
                  &As[b][h*8192 + task*8]);
    }
  };
  auto stageB = [&](int kt, int b, int h){
    #pragma unroll
    for (int r2 = 0; r2 < 2; ++r2){
      int task = r2*512 + t;
      int ps = task >> 3, ch = task & 7, sch = ch ^ (ps & 7);
      int lr = h*32 + ((ps >> 5) << 6) + (ps & 31);
      gload_lds16(wdA + (size_t)(ncol0 + lr)*KD + kt*64 + sch*8,
                  &Bs[b][h*8192 + task*8]);
    }
  };

  bf16x8 af[4][2], bLo[2][2], bHi[2][2];
  auto readAh = [&](int b, int qa){
    #pragma unroll
    for (int mi = 0; mi < 4; ++mi){
      int r = wm*128 + qa*64 + mi*16 + (lane & 15);
      int q = r >> 6, qs = ((q & 1) << 1) | (q >> 1);
      int pr = qs*64 + (r & 63);
      #pragma unroll
      for (int kk = 0; kk < 2; ++kk){
        int pc = (kk*4 + (lane >> 4)) ^ (pr & 7);
        af[mi][kk] = *(const bf16x8*)&As[b][pr*64 + pc*8];
      }
    }
  };
  auto readBh = [&](bf16x8 (&bf)[2][2], int b, int hb){
    #pragma unroll
    for (int ni = 0; ni < 2; ++ni){
      int rB = wn*64 + hb*32 + ni*16 + (lane & 15);
      int pr = ((rB >> 5) & 1)*128 + (rB >> 6)*32 + (rB & 31);
      #pragma unroll
      for (int kk = 0; kk < 2; ++kk){
        int pc = (kk*4 + (lane >> 4)) ^ (pr & 7);
        bf[ni][kk] = *(const bf16x8*)&Bs[b][pr*64 + pc*8];
      }
    }
  };
  auto mfmaQ = [&](bf16x8 (&bf)[2][2], int qa, int hb){
    #pragma unroll
    for (int kk = 0; kk < 2; ++kk)
      #pragma unroll
      for (int ni = 0; ni < 2; ++ni)
        #pragma unroll
        for (int mi = 0; mi < 4; ++mi)
          acc[qa*4+mi][hb*2+ni] = MFMA_BF16(af[mi][kk], bf[ni][kk], acc[qa*4+mi][hb*2+ni]);
  };

  stageA(kst,0,0); stageB(kst,0,0); stageB(kst,0,1); stageA(kst,0,1);
  stageA(kst+1,1,0); stageB(kst+1,1,0); stageB(kst+1,1,1);
  asm volatile("s_waitcnt vmcnt(8)" ::: "memory");
  SBAR();

  const int nit = (ksteps - 1) >> 1;      // full 2-tile iterations
  for (int it = 0; it < nit; ++it){
    int kt = kst + 2*it;
    int ktA = (kt+2 < kend) ? kt+2 : kend-1;
    int ktB = (kt+3 < kend) ? kt+3 : kend-1;
    readAh(0, 0); readBh(bLo, 0, 0);
    stageA(kt+1, 1, 1);
    SCHED_FENCE(); SBAR(); LGK0(); SCHED_FENCE();
    PRIO1(); mfmaQ(bLo, 0, 0); PRIO0();
    VMC6(); SBAR();
    readBh(bHi, 0, 1);
    stageA(ktA, 0, 0);
    SCHED_FENCE(); SBAR(); LGK0(); SCHED_FENCE();
    PRIO1(); mfmaQ(bHi, 0, 1); PRIO0();
    VMC6(); SBAR();
    readAh(0, 1);
    stageB(ktA, 0, 0);
    SCHED_FENCE(); SBAR(); LGK0(); SCHED_FENCE();
    PRIO1(); mfmaQ(bHi, 1, 1); PRIO0();
    VMC6(); SBAR();
    stageB(ktA, 0, 1);
    SCHED_FENCE(); SBAR(); SCHED_FENCE();
    PRIO1(); mfmaQ(bLo, 1, 0); PRIO0();
    VMC6(); SBAR();
    readAh(1, 0); readBh(bLo, 1, 0);
    stageA(ktA, 0, 1);
    SCHED_FENCE(); SBAR(); LGK0(); SCHED_FENCE();
    PRIO1(); mfmaQ(bLo, 0, 0); PRIO0();
    VMC6(); SBAR();
    readBh(bHi, 1, 1);
    stageA(ktB, 1, 0);
    SCHED_FENCE(); SBAR(); LGK0(); SCHED_FENCE();
    PRIO1(); mfmaQ(bHi, 0, 1); PRIO0();
    VMC6(); SBAR();
    readAh(1, 1);
    stageB(ktB, 1, 0);
    SCHED_FENCE(); SBAR(); LGK0(); SCHED_FENCE();
    PRIO1(); mfmaQ(bHi, 1, 1); PRIO0();
    VMC6(); SBAR();
    stageB(ktB, 1, 1);
    SCHED_FENCE(); SBAR(); SCHED_FENCE();
    PRIO1(); mfmaQ(bLo, 1, 0); PRIO0();
    VMC6(); SBAR();
  }

  // TAIL-PARITY FIX: for EVEN ksteps the last tile's A-hi half is staged by
  // the (nonexistent) next iteration's p1 -> stage it here. Safe: all reads
  // of that region finished before the loop's final barrier, and the tail
  // reads only after vmcnt(0)+barrier below.
  if ((ksteps & 1) == 0)
    stageA(kend-1, 1, 1);

  asm volatile("s_waitcnt vmcnt(0)" ::: "memory");
  SBAR();
  for (int jt = 2*nit; jt < ksteps; ++jt){
    int b = jt & 1;
    readAh(b, 0); readBh(bLo, b, 0); readBh(bHi, b, 1);
    LGK0(); SCHED_FENCE();
    mfmaQ(bLo, 0, 0); mfmaQ(bHi, 0, 1);
    readAh(b, 1);
    LGK0(); SCHED_FENCE();
    mfmaQ(bHi, 1, 1); mfmaQ(bLo, 1, 0);
  }

  // epilogue: partial[z] = acc (accumulate across chunk passes)
  float* pp = pout + (size_t)z * T * H;
  #pragma unroll
  for (int j = 0; j < 4; ++j){
    int h0 = ncol0 + wn*64 + j*16;
    if (h0 < H){
      int h = h0 + (lane & 15);
      #pragma unroll
      for (int mi = 0; mi < 8; ++mi){
        #pragma unroll
        for (int r = 0; r < 4; ++r){
          int trw = trow0 + wm*128 + mi*16 + (lane >> 4)*4 + r;
          size_t oi = (size_t)trw * H + h;
          float v = acc[mi][j][r];
          if (accum) v += pp[oi];
          pp[oi] = v;
        }
      }
    }
  }
}

extern "C" void kernel_launch(void* const* d_in, const int* in_sizes, int n_in,
                              void* d_out, int out_size, void* d_ws, size_t ws_size,
                              hipStream_t stream) {
  const float* hs  = (const float*)d_in[0];
  const float* rwt = (const float*)d_in[1];
  const float* Wg  = (const float*)d_in[2];
  const float* bg  = (const float*)d_in[3];
  const float* Wu  = (const float*)d_in[4];
  const float* bu  = (const float*)d_in[5];
  const float* Wd  = (const float*)d_in[6];
  const float* bd  = (const float*)d_in[7];
  float* out = (float*)d_out;

  const size_t xbytes = (size_t)T * H * 2;            // 11.8 MB
  const size_t poutB  = (size_t)NZ * T * H * 4;       // 94.4 MB
  // per expert: inter column block + paired wGU + wdA column block
  const size_t perE = (size_t)T*D*2 + (size_t)NPR*H*2 + (size_t)HP*D*2; // 63.4 MB

  long long avail = (long long)ws_size - (long long)(xbytes + poutB);
  int EC = (int)(avail / (long long)perE);
  if (EC > E) EC = E;
  EC -= EC % 4;                                        // split-K=4 divisibility
  if (EC < 4) EC = 4;
  const int KD = EC * D;

  unsigned short* xb    = (unsigned short*)d_ws;
  float*          pout  = (float*)((char*)d_ws + xbytes);
  unsigned short* inter = (unsigned short*)((char*)d_ws + xbytes + poutB);
  unsigned short* wGU   = inter + (size_t)T * KD;
  unsigned short* wdA   = wGU + (size_t)EC * NPR * H;

  cvt_kernel<<<(T*H/8 + 255)/256, 256, 0, stream>>>(hs, xb, T*H/8);

  for (int e0 = 0; e0 < E; e0 += EC){
    int ec = (E - e0 < EC) ? (E - e0) : EC;            // always == EC (E=16)
    tcvt_kernel<<<dim3(45,46,ec), 256, 0, stream>>>(
        Wg + (size_t)e0*H*D, wGU, 0, (size_t)NPR*H, (size_t)H);
    tcvt_kernel<<<dim3(45,46,ec), 256, 0, stream>>>(
        Wu + (size_t)e0*H*D, wGU, 1, (size_t)NPR*H, (size_t)H);
    tcvt_kernel<<<dim3(45,48,ec), 256, 0, stream>>>(
        Wd + (size_t)e0*H*D, wdA, 2, (size_t)D, (size_t)KD);
    gateup_kernel<<<dim3(8, 23, ec), 512, 0, stream>>>(
        xb, wGU, bg, bu, rwt, inter, e0, KD);
    down_kernel<<<dim3(8, 12, NZ), 512, 0, stream>>>(
        inter, wdA, pout, ec*NKT, KD, e0 != 0);
  }
  reduce_kernel<<<(T*H/4 + 255)/256, 256, 0, stream>>>(pout, rwt, bd, out, T*H/4);
}

// Round 14
// 2010.278 us; speedup vs baseline: 2.2116x; 1.0508x over previous
//
#include <hip/hip_runtime.h>
#include <cstdint>

// GptOssExpertsLinear: E=16, H=D=2880, T=2048.
// out[t,h] = sum_e rw[t,e] * ( act(x@Wg[e]+bg, x@Wu[e]+bu) @ Wd[e] + bd )
// R14 = R13 with down split-K NZ=4->8: 768 blocks = exactly 3 full CU rounds
// (384 was 1.5 rounds -> half-idle round 2, ~25% of down wall). EC forced
// multiple of 8 (ksteps divisibility). Reduce sums 8 partials.
// Structure: rw folded into gateup -> down is ONE GEMM over concatenated
// K = EC*2880, 8-phase 256x256 template with tail-parity fix. Bias via
// rank-16 rw@bd in reduce. Gateup pairing pad 2944.

#define ALPHA 1.702f
#define LIMIT 7.0f

static constexpr int E = 16;
static constexpr int H = 2880;
static constexpr int D = 2880;
static constexpr int T = 2048;
static constexpr int NKT = 45;       // gateup K-steps of 64 (K=2880)
static constexpr int NPR = 5888;     // paired gate|up rows (2*2944)
static constexpr int HP  = 3072;     // padded H for down N
static constexpr int NZ  = 8;        // down split-K partials (768 blocks = 3 rounds)

typedef float        f32x4  __attribute__((ext_vector_type(4)));
typedef short        bf16x8 __attribute__((ext_vector_type(8)));

#define MFMA_BF16(a,b,c) __builtin_amdgcn_mfma_f32_16x16x32_bf16((a),(b),(c),0,0,0)
#define SBAR()        __builtin_amdgcn_s_barrier()
#define SCHED_FENCE() __builtin_amdgcn_sched_barrier(0)
#define PRIO1()       __builtin_amdgcn_s_setprio(1)
#define PRIO0()       __builtin_amdgcn_s_setprio(0)
#define LGK0()        asm volatile("s_waitcnt lgkmcnt(0)" ::: "memory")
#define VMC6()        asm volatile("s_waitcnt vmcnt(6)" ::: "memory")

__device__ __forceinline__ unsigned short f2bf(float f){
  unsigned u = __builtin_bit_cast(unsigned, f);
  u += 0x7fffu + ((u >> 16) & 1u);
  return (unsigned short)(u >> 16);
}
__device__ __forceinline__ unsigned pack2(float a, float b){
  return (unsigned)f2bf(a) | ((unsigned)f2bf(b) << 16);
}

__device__ __forceinline__ void gload_lds16(const void* g, void* l){
  __builtin_amdgcn_global_load_lds((const __attribute__((address_space(1))) unsigned*)g,
                                   (__attribute__((address_space(3))) unsigned*)l,
                                   16, 0, 0);
}

// x fp32 -> bf16, 8 elems/thread
__global__ void cvt_kernel(const float* __restrict__ in, unsigned short* __restrict__ ob, int n8){
  int i = blockIdx.x * 256 + threadIdx.x;
  if (i < n8){
    float4 a = ((const float4*)in)[2*i];
    float4 b = ((const float4*)in)[2*i+1];
    uint4 o;
    o.x = pack2(a.x, a.y); o.y = pack2(a.z, a.w);
    o.z = pack2(b.x, b.y); o.w = pack2(b.z, b.w);
    ((uint4*)ob)[i] = o;
  }
}

// W fp32 -> bf16 transpose with row remap; zero-pad rows beyond D.
// mode 0: dst row = (c/32)*64 + c%32       (gate half of paired layout)
// mode 1: dst row = (c/32)*64 + c%32 + 32  (up half)
// mode 2: dst row = c                      (plain transpose, down weights)
// dst element = dst + z*expStride + rowp*rowStride + k
__global__ __launch_bounds__(256) void tcvt_kernel(
    const float* __restrict__ src, unsigned short* __restrict__ dst,
    int mode, size_t expStride, size_t rowStride)
{
  __shared__ unsigned short tl[64*72];
  const int t = threadIdx.x;
  const float* s = src + (size_t)blockIdx.z * H * D;
  unsigned short* o = dst + (size_t)blockIdx.z * expStride;
  const int r0 = blockIdx.x * 64, c0 = blockIdx.y * 64;

  if (c0 < D){
    int rr = t >> 2;
    #pragma unroll
    for (int p = 0; p < 4; ++p){
      int cc = ((t & 3) + p*4) * 4;
      float4 v = *(const float4*)(s + (size_t)(r0 + rr)*D + c0 + cc);
      tl[(cc+0)*72 + rr] = f2bf(v.x);
      tl[(cc+1)*72 + rr] = f2bf(v.y);
      tl[(cc+2)*72 + rr] = f2bf(v.z);
      tl[(cc+3)*72 + rr] = f2bf(v.w);
    }
    __syncthreads();
    #pragma unroll
    for (int p = 0; p < 2; ++p){
      int task = p*256 + t;
      int cl = task >> 3, ch = task & 7;
      int c = c0 + cl;
      int rowp = (mode < 2) ? ((c >> 5)*64 + (c & 31) + mode*32) : c;
      bf16x8 v = *(const bf16x8*)&tl[cl*72 + ch*8];
      *(bf16x8*)(o + (size_t)rowp*rowStride + r0 + ch*8) = v;
    }
  } else {
    #pragma unroll
    for (int p = 0; p < 2; ++p){
      int task = p*256 + t;
      int cl = task >> 3, ch = task & 7;
      int c = c0 + cl;
      int rowp = (mode < 2) ? ((c >> 5)*64 + (c & 31) + mode*32) : c;
      bf16x8 z = (bf16x8){0,0,0,0,0,0,0,0};
      *(bf16x8*)(o + (size_t)rowp*rowStride + r0 + ch*8) = z;
    }
  }
}

// sum NZ split-K partials + rank-E bias term rw@bd -> out
__global__ void reduce_kernel(const float* __restrict__ p,
                              const float* __restrict__ rw,
                              const float* __restrict__ bd,
                              float* __restrict__ out, int n4){
  int i = blockIdx.x * 256 + threadIdx.x;
  if (i < n4){
    int t  = i / (H/4);
    int h4 = (i % (H/4)) * 4;
    f32x4 a = ((const f32x4*)p)[i];
    #pragma unroll
    for (int z = 1; z < NZ; ++z)
      a += ((const f32x4*)(p + (size_t)z * T * H))[i];
    #pragma unroll
    for (int e = 0; e < E; ++e){
      float r = rw[t*E + e];
      f32x4 b = *(const f32x4*)(bd + (size_t)e*H + h4);
      a += r * b;
    }
    ((f32x4*)out)[i] = a;
  }
}

// ---------------- gate+up fused GEMM + activation (8-phase 256x256) --------
// grid (8, 23, ec); 512 thr = 8 waves (2M x 4N); wave tile 128x64 paired.
__global__ __launch_bounds__(512, 2) void gateup_kernel(
    const unsigned short* __restrict__ xb,    // [T][H] bf16
    const unsigned short* __restrict__ wGU,   // [ec][5888][H] paired bf16
    const float* __restrict__ bg,
    const float* __restrict__ bu,
    const float* __restrict__ rw,             // [T][E]
    unsigned short* __restrict__ inter,       // [T][KD] bf16 (rw-scaled)
    int e0, int KD)
{
  __shared__ short As[2][256*64];   // 64KB (quarter-interleaved rows)
  __shared__ short Bs[2][256*64];   // 64KB => 128KB total

  const int t = threadIdx.x, lane = t & 63, wv = t >> 6;
  const int wm = wv >> 2, wn = wv & 3;

  int nbx = gridDim.x, nby = gridDim.y;
  int lin = blockIdx.x + nbx*(blockIdx.y + nby*blockIdx.z);
  int per = (nbx*nby*gridDim.z) >> 3;
  int id2 = (lin & 7)*per + (lin >> 3);
  int bx = id2 % nbx; int rem = id2 / nbx;
  int by = rem % nby; int ez = rem / nby;

  const int trow0 = bx*256, ncol0 = by*256;
  const int e = e0 + ez;
  const unsigned short* wg = wGU + (size_t)ez * NPR * H;

  f32x4 acc[8][4];
  #pragma unroll
  for (int i = 0; i < 8; ++i)
    #pragma unroll
    for (int j = 0; j < 4; ++j) acc[i][j] = (f32x4){0.f,0.f,0.f,0.f};

  auto stageA = [&](int kt, int b, int h){
    #pragma unroll
    for (int r2 = 0; r2 < 2; ++r2){
      int task = r2*512 + t;
      int ps = task >> 3, ch = task & 7, sch = ch ^ (ps & 7);
      int lr = h*64 + (ps & 63) + ((ps >> 6) << 7);
      gload_lds16(xb + (size_t)(trow0 + lr)*H + kt*64 + sch*8,
                  &As[b][h*8192 + task*8]);
    }
  };
  auto stageB = [&](int kt, int b, int h){
    #pragma unroll
    for (int r2 = 0; r2 < 2; ++r2){
      int task = r2*512 + t;
      int ps = task >> 3, ch = task & 7, sch = ch ^ (ps & 7);
      int lr = h*32 + ((ps >> 5) << 6) + (ps & 31);
      gload_lds16(wg + (size_t)(ncol0 + lr)*H + kt*64 + sch*8,
                  &Bs[b][h*8192 + task*8]);
    }
  };

  bf16x8 af[4][2], bLo[2][2], bHi[2][2];
  auto readAh = [&](int b, int qa){
    #pragma unroll
    for (int mi = 0; mi < 4; ++mi){
      int r = wm*128 + qa*64 + mi*16 + (lane & 15);
      int q = r >> 6, qs = ((q & 1) << 1) | (q >> 1);
      int pr = qs*64 + (r & 63);
      #pragma unroll
      for (int kk = 0; kk < 2; ++kk){
        int pc = (kk*4 + (lane >> 4)) ^ (pr & 7);
        af[mi][kk] = *(const bf16x8*)&As[b][pr*64 + pc*8];
      }
    }
  };
  auto readBh = [&](bf16x8 (&bf)[2][2], int b, int hb){
    #pragma unroll
    for (int ni = 0; ni < 2; ++ni){
      int rB = wn*64 + hb*32 + ni*16 + (lane & 15);
      int pr = ((rB >> 5) & 1)*128 + (rB >> 6)*32 + (rB & 31);
      #pragma unroll
      for (int kk = 0; kk < 2; ++kk){
        int pc = (kk*4 + (lane >> 4)) ^ (pr & 7);
        bf[ni][kk] = *(const bf16x8*)&Bs[b][pr*64 + pc*8];
      }
    }
  };
  auto mfmaQ = [&](bf16x8 (&bf)[2][2], int qa, int hb){
    #pragma unroll
    for (int kk = 0; kk < 2; ++kk)
      #pragma unroll
      for (int ni = 0; ni < 2; ++ni)
        #pragma unroll
        for (int mi = 0; mi < 4; ++mi)
          acc[qa*4+mi][hb*2+ni] = MFMA_BF16(af[mi][kk], bf[ni][kk], acc[qa*4+mi][hb*2+ni]);
  };

  stageA(0,0,0); stageB(0,0,0); stageB(0,0,1); stageA(0,0,1);
  stageA(1,1,0); stageB(1,1,0); stageB(1,1,1);
  asm volatile("s_waitcnt vmcnt(8)" ::: "memory");
  SBAR();

  for (int it = 0; it < 22; ++it){
    int kt = 2*it;
    int ktA = (kt+2 < NKT) ? kt+2 : NKT-1;
    int ktB = (kt+3 < NKT) ? kt+3 : NKT-1;
    readAh(0, 0); readBh(bLo, 0, 0);
    stageA(kt+1, 1, 1);
    SCHED_FENCE(); SBAR(); LGK0(); SCHED_FENCE();
    PRIO1(); mfmaQ(bLo, 0, 0); PRIO0();
    VMC6(); SBAR();
    readBh(bHi, 0, 1);
    stageA(ktA, 0, 0);
    SCHED_FENCE(); SBAR(); LGK0(); SCHED_FENCE();
    PRIO1(); mfmaQ(bHi, 0, 1); PRIO0();
    VMC6(); SBAR();
    readAh(0, 1);
    stageB(ktA, 0, 0);
    SCHED_FENCE(); SBAR(); LGK0(); SCHED_FENCE();
    PRIO1(); mfmaQ(bHi, 1, 1); PRIO0();
    VMC6(); SBAR();
    stageB(ktA, 0, 1);
    SCHED_FENCE(); SBAR(); SCHED_FENCE();
    PRIO1(); mfmaQ(bLo, 1, 0); PRIO0();
    VMC6(); SBAR();
    readAh(1, 0); readBh(bLo, 1, 0);
    stageA(ktA, 0, 1);
    SCHED_FENCE(); SBAR(); LGK0(); SCHED_FENCE();
    PRIO1(); mfmaQ(bLo, 0, 0); PRIO0();
    VMC6(); SBAR();
    readBh(bHi, 1, 1);
    stageA(ktB, 1, 0);
    SCHED_FENCE(); SBAR(); LGK0(); SCHED_FENCE();
    PRIO1(); mfmaQ(bHi, 0, 1); PRIO0();
    VMC6(); SBAR();
    readAh(1, 1);
    stageB(ktB, 1, 0);
    SCHED_FENCE(); SBAR(); LGK0(); SCHED_FENCE();
    PRIO1(); mfmaQ(bHi, 1, 1); PRIO0();
    VMC6(); SBAR();
    stageB(ktB, 1, 1);
    SCHED_FENCE(); SBAR(); SCHED_FENCE();
    PRIO1(); mfmaQ(bLo, 1, 0); PRIO0();
    VMC6(); SBAR();
  }

  asm volatile("s_waitcnt vmcnt(0)" ::: "memory");
  SBAR();
  readAh(0, 0); readBh(bLo, 0, 0); readBh(bHi, 0, 1);
  LGK0(); SCHED_FENCE();
  mfmaQ(bLo, 0, 0); mfmaQ(bHi, 0, 1);
  readAh(0, 1);
  LGK0(); SCHED_FENCE();
  mfmaQ(bHi, 1, 1); mfmaQ(bLo, 1, 0);

  // epilogue: bias + clamp + glu, scaled by rw -> inter[t][ez*D + d]
  const float* bgp = bg + (size_t)e * D;
  const float* bup = bu + (size_t)e * D;
  unsigned short* ip = inter + (size_t)ez * D;
  const int dbase = (by*4 + wn) * 32;
  #pragma unroll
  for (int g = 0; g < 2; ++g){
    int d0 = dbase + g*16;
    if (d0 < D){
      int d = d0 + (lane & 15);
      float bgv = bgp[d], buv = bup[d];
      #pragma unroll
      for (int mi = 0; mi < 8; ++mi){
        #pragma unroll
        for (int r = 0; r < 4; ++r){
          int trw = trow0 + wm*128 + mi*16 + (lane >> 4)*4 + r;
          float gv = acc[mi][g][r] + bgv;
          float uv = acc[mi][g+2][r] + buv;
          gv = fminf(gv, LIMIT);
          uv = fminf(fmaxf(uv, -LIMIT), LIMIT);
          float glu = gv / (1.f + __expf(-ALPHA * gv));
          float rv = rw[trw*E + e];
          ip[(size_t)trw * KD + d] = f2bf(rv * (uv + 1.f) * glu);
        }
      }
    }
  }
}

// ---------------- down: single GEMM over concatenated K, split-K=8 ---------
// grid (8, 12, NZ); 512 thr = 8 waves; tile 256x256; generic trip count.
__global__ __launch_bounds__(512, 2) void down_kernel(
    const unsigned short* __restrict__ inter, // [T][KD] bf16 (rw-scaled)
    const unsigned short* __restrict__ wdA,   // [3072][KD] bf16 (pad rows 0)
    float* __restrict__ pout,                 // [NZ][T][H] fp32 partials
    int nk64, int KD, int accum)
{
  __shared__ short As[2][256*64];
  __shared__ short Bs[2][256*64];

  const int t = threadIdx.x, lane = t & 63, wv = t >> 6;
  const int wm = wv >> 2, wn = wv & 3;

  int nbx = gridDim.x, nby = gridDim.y;
  int lin = blockIdx.x + nbx*(blockIdx.y + nby*blockIdx.z);
  int per = (nbx*nby*gridDim.z) >> 3;
  int id2 = (lin & 7)*per + (lin >> 3);
  int bx = id2 % nbx; int rem = id2 / nbx;
  int by = rem % nby; int z  = rem / nby;

  const int trow0 = bx*256, ncol0 = by*256;
  const int ksteps = nk64 / NZ;           // per split-K slice
  const int kst = z * ksteps, kend = kst + ksteps;

  f32x4 acc[8][4];
  #pragma unroll
  for (int i = 0; i < 8; ++i)
    #pragma unroll
    for (int j = 0; j < 4; ++j) acc[i][j] = (f32x4){0.f,0.f,0.f,0.f};

  auto stageA = [&](int kt, int b, int h){
    #pragma unroll
    for (int r2 = 0; r2 < 2; ++r2){
      int task = r2*512 + t;
      int ps = task >> 3, ch = task & 7, sch = ch ^ (ps & 7);
      int lr = h*64 + (ps & 63) + ((ps >> 6) << 7);
      gload_lds16(inter + (size_t)(trow0 + lr)*KD + kt*64 + sch*8,
                  &As[b][h*8192 + task*8]);
    }
  };
  auto stageB = [&](int kt, int b, int h){
    #pragma unroll
    for (int r2 = 0; r2 < 2; ++r2){
      int task = r2*512 + t;
      int ps = task >> 3, ch = task & 7, sch = ch ^ (ps & 7);
      int lr = h*32 + ((ps >> 5) << 6) + (ps & 31);
      gload_lds16(wdA + (size_t)(ncol0 + lr)*KD + kt*64 + sch*8,
                  &Bs[b][h*8192 + task*8]);
    }
  };

  bf16x8 af[4][2], bLo[2][2], bHi[2][2];
  auto readAh = [&](int b, int qa){
    #pragma unroll
    for (int mi = 0; mi < 4; ++mi){
      int r = wm*128 + qa*64 + mi*16 + (lane & 15);
      int q = r >> 6, qs = ((q & 1) << 1) | (q >> 1);
      int pr = qs*64 + (r & 63);
      #pragma unroll
      for (int kk = 0; kk < 2; ++kk){
        int pc = (kk*4 + (lane >> 4)) ^ (pr & 7);
        af[mi][kk] = *(const bf16x8*)&As[b][pr*64 + pc*8];
      }
    }
  };
  auto readBh = [&](bf16x8 (&bf)[2][2], int b, int hb){
    #pragma unroll
    for (int ni = 0; ni < 2; ++ni){
      int rB = wn*64 + hb*32 + ni*16 + (lane & 15);
      int pr = ((rB >> 5) & 1)*128 + (rB >> 6)*32 + (rB & 31);
      #pragma unroll
      for (int kk = 0; kk < 2; ++kk){
        int pc = (kk*4 + (lane >> 4)) ^ (pr & 7);
        bf[ni][kk] = *(const bf16x8*)&Bs[b][pr*64 + pc*8];
      }
    }
  };
  auto mfmaQ = [&](bf16x8 (&bf)[2][2], int qa, int hb){
    #pragma unroll
    for (int kk = 0; kk < 2; ++kk)
      #pragma unroll
      for (int ni = 0; ni < 2; ++ni)
        #pragma unroll
        for (int mi = 0; mi < 4; ++mi)
          acc[qa*4+mi][hb*2+ni] = MFMA_BF16(af[mi][kk], bf[ni][kk], acc[qa*4+mi][hb*2+ni]);
  };

  stageA(kst,0,0); stageB(kst,0,0); stageB(kst,0,1); stageA(kst,0,1);
  stageA(kst+1,1,0); stageB(kst+1,1,0); stageB(kst+1,1,1);
  asm volatile("s_waitcnt vmcnt(8)" ::: "memory");
  SBAR();

  const int nit = (ksteps - 1) >> 1;      // full 2-tile iterations
  for (int it = 0; it < nit; ++it){
    int kt = kst + 2*it;
    int ktA = (kt+2 < kend) ? kt+2 : kend-1;
    int ktB = (kt+3 < kend) ? kt+3 : kend-1;
    readAh(0, 0); readBh(bLo, 0, 0);
    stageA(kt+1, 1, 1);
    SCHED_FENCE(); SBAR(); LGK0(); SCHED_FENCE();
    PRIO1(); mfmaQ(bLo, 0, 0); PRIO0();
    VMC6(); SBAR();
    readBh(bHi, 0, 1);
    stageA(ktA, 0, 0);
    SCHED_FENCE(); SBAR(); LGK0(); SCHED_FENCE();
    PRIO1(); mfmaQ(bHi, 0, 1); PRIO0();
    VMC6(); SBAR();
    readAh(0, 1);
    stageB(ktA, 0, 0);
    SCHED_FENCE(); SBAR(); LGK0(); SCHED_FENCE();
    PRIO1(); mfmaQ(bHi, 1, 1); PRIO0();
    VMC6(); SBAR();
    stageB(ktA, 0, 1);
    SCHED_FENCE(); SBAR(); SCHED_FENCE();
    PRIO1(); mfmaQ(bLo, 1, 0); PRIO0();
    VMC6(); SBAR();
    readAh(1, 0); readBh(bLo, 1, 0);
    stageA(ktA, 0, 1);
    SCHED_FENCE(); SBAR(); LGK0(); SCHED_FENCE();
    PRIO1(); mfmaQ(bLo, 0, 0); PRIO0();
    VMC6(); SBAR();
    readBh(bHi, 1, 1);
    stageA(ktB, 1, 0);
    SCHED_FENCE(); SBAR(); LGK0(); SCHED_FENCE();
    PRIO1(); mfmaQ(bHi, 0, 1); PRIO0();
    VMC6(); SBAR();
    readAh(1, 1);
    stageB(ktB, 1, 0);
    SCHED_FENCE(); SBAR(); LGK0(); SCHED_FENCE();
    PRIO1(); mfmaQ(bHi, 1, 1); PRIO0();
    VMC6(); SBAR();
    stageB(ktB, 1, 1);
    SCHED_FENCE(); SBAR(); SCHED_FENCE();
    PRIO1(); mfmaQ(bLo, 1, 0); PRIO0();
    VMC6(); SBAR();
  }

  // TAIL-PARITY FIX: for EVEN ksteps the last tile's A-hi half is staged by
  // the (nonexistent) next iteration's p1 -> stage it here. Safe: all reads
  // of that region finished before the loop's final barrier, and the tail
  // reads only after vmcnt(0)+barrier below.
  if ((ksteps & 1) == 0)
    stageA(kend-1, 1, 1);

  asm volatile("s_waitcnt vmcnt(0)" ::: "memory");
  SBAR();
  for (int jt = 2*nit; jt < ksteps; ++jt){
    int b = jt & 1;
    readAh(b, 0); readBh(bLo, b, 0); readBh(bHi, b, 1);
    LGK0(); SCHED_FENCE();
    mfmaQ(bLo, 0, 0); mfmaQ(bHi, 0, 1);
    readAh(b, 1);
    LGK0(); SCHED_FENCE();
    mfmaQ(bHi, 1, 1); mfmaQ(bLo, 1, 0);
  }

  // epilogue: partial[z] = acc (accumulate across chunk passes)
  float* pp = pout + (size_t)z * T * H;
  #pragma unroll
  for (int j = 0; j < 4; ++j){
    int h0 = ncol0 + wn*64 + j*16;
    if (h0 < H){
      int h = h0 + (lane & 15);
      #pragma unroll
      for (int mi = 0; mi < 8; ++mi){
        #pragma unroll
        for (int r = 0; r < 4; ++r){
          int trw = trow0 + wm*128 + mi*16 + (lane >> 4)*4 + r;
          size_t oi = (size_t)trw * H + h;
          float v = acc[mi][j][r];
          if (accum) v += pp[oi];
          pp[oi] = v;
        }
      }
    }
  }
}

extern "C" void kernel_launch(void* const* d_in, const int* in_sizes, int n_in,
                              void* d_out, int out_size, void* d_ws, size_t ws_size,
                              hipStream_t stream) {
  const float* hs  = (const float*)d_in[0];
  const float* rwt = (const float*)d_in[1];
  const float* Wg  = (const float*)d_in[2];
  const float* bg  = (const float*)d_in[3];
  const float* Wu  = (const float*)d_in[4];
  const float* bu  = (const float*)d_in[5];
  const float* Wd  = (const float*)d_in[6];
  const float* bd  = (const float*)d_in[7];
  float* out = (float*)d_out;

  const size_t xbytes = (size_t)T * H * 2;            // 11.8 MB
  const size_t poutB  = (size_t)NZ * T * H * 4;       // 188.7 MB
  // per expert: inter column block + paired wGU + wdA column block
  const size_t perE = (size_t)T*D*2 + (size_t)NPR*H*2 + (size_t)HP*D*2; // 63.4 MB

  long long avail = (long long)ws_size - (long long)(xbytes + poutB);
  int EC = (int)(avail / (long long)perE);
  if (EC > E) EC = E;
  EC -= EC % 8;                                        // ksteps divisibility (NZ=8, 45 odd)
  if (EC < 8) EC = 8;
  const int KD = EC * D;

  unsigned short* xb    = (unsigned short*)d_ws;
  float*          pout  = (float*)((char*)d_ws + xbytes);
  unsigned short* inter = (unsigned short*)((char*)d_ws + xbytes + poutB);
  unsigned short* wGU   = inter + (size_t)T * KD;
  unsigned short* wdA   = wGU + (size_t)EC * NPR * H;

  cvt_kernel<<<(T*H/8 + 255)/256, 256, 0, stream>>>(hs, xb, T*H/8);

  for (int e0 = 0; e0 < E; e0 += EC){
    int ec = (E - e0 < EC) ? (E - e0) : EC;            // == EC (E=16, EC in {8,16})
    tcvt_kernel<<<dim3(45,46,ec), 256, 0, stream>>>(
        Wg + (size_t)e0*H*D, wGU, 0, (size_t)NPR*H, (size_t)H);
    tcvt_kernel<<<dim3(45,46,ec), 256, 0, stream>>>(
        Wu + (size_t)e0*H*D, wGU, 1, (size_t)NPR*H, (size_t)H);
    tcvt_kernel<<<dim3(45,48,ec), 256, 0, stream>>>(
        Wd + (size_t)e0*H*D, wdA, 2, (size_t)D, (size_t)KD);
    gateup_kernel<<<dim3(8, 23, ec), 512, 0, stream>>>(
        xb, wGU, bg, bu, rwt, inter, e0, KD);
    down_kernel<<<dim3(8, 12, NZ), 512, 0, stream>>>(
        inter, wdA, pout, ec*NKT, KD, e0 != 0);
  }
  reduce_kernel<<<(T*H/4 + 255)/256, 256, 0, stream>>>(pout, rwt, bd, out, T*H/4);
}